// Round 3
// baseline (2208.948 us; speedup 1.0000x reference)
//
#include <hip/hip_runtime.h>
#include <math.h>
#include <stdint.h>

typedef unsigned short u16;
typedef unsigned int   u32;
typedef __attribute__((ext_vector_type(8))) short bf16x8;
typedef __attribute__((ext_vector_type(4))) float f32x4;

#define EDIM 256
#define HDIM 128
#define TLEN 128
#define NUTT 1024
#define UU   32
#define NBU  16

// workspace layout (bytes)
#define WS_FLAG 0
#define WS_LENS 64
#define WS_TAB  4608
#define WS_COPY 8192
#define WS_OF   18874368LL   // bf16 o_f [NUTT][TLEN][HDIM] = 33.55 MB; total 50 MB

#define MFMA16(a, b, c) __builtin_amdgcn_mfma_f32_16x16x32_bf16((a), (b), (c), 0, 0, 0)

__constant__ int G_SZ[18] = {7680000, 98304, 49152, 384, 384, 98304, 49152, 384, 384,
                             65536, 256, 65536, 65536, 256, 65536, 256, 65536, 256};

__device__ __forceinline__ float b2f(u16 b) {
    u32 u = ((u32)b) << 16; float f; __builtin_memcpy(&f, &u, 4); return f;
}
__device__ __forceinline__ u16 f2b(float f) {   // RNE, finite inputs only
    u32 u; __builtin_memcpy(&u, &f, 4);
    u32 r = u + 0x7FFFu + ((u >> 16) & 1u);
    return (u16)(r >> 16);
}
__device__ __forceinline__ float fsigmoid(float x) { return 1.0f / (1.0f + __expf(-x)); }
__device__ __forceinline__ float ftanh(float x) { return 1.0f - 2.0f / (__expf(2.0f * x) + 1.0f); }

// -------------------------------------------------------------------------
// k_detect: decide bf16 vs fp32 by scanning emb bits; build pointer table.
// -------------------------------------------------------------------------
__global__ void k_detect(void* ws,
                         const void* a0, const void* a1, const void* a2, const void* a3,
                         const void* a4, const void* a5, const void* a6, const void* a7,
                         const void* a8, const void* a9, const void* a10, const void* a11,
                         const void* a12, const void* a13, const void* a14, const void* a15,
                         const void* a16, const void* a17) {
    const u16* p = (const u16*)a0;
    int cnt = 0;
    for (int i = threadIdx.x; i < 65536; i += 64)
        cnt += ((p[i] & 0x7F80) == 0x7F80) ? 1 : 0;
#pragma unroll
    for (int o = 32; o > 0; o >>= 1) cnt += __shfl_down(cnt, o);
    if (threadIdx.x == 0) {
        const void* orig[18] = {a0,a1,a2,a3,a4,a5,a6,a7,a8,a9,a10,a11,a12,a13,a14,a15,a16,a17};
        const int flag = (cnt > 0) ? 1 : 0;
        *(int*)((char*)ws + WS_FLAG) = flag;
        const u16** tab = (const u16**)((char*)ws + WS_TAB);
        char* base = (char*)ws + WS_COPY;
        long long cum = 0;
        for (int a = 0; a < 18; ++a) {
            tab[a] = flag ? (const u16*)(base + cum * 2) : (const u16*)orig[a];
            cum += G_SZ[a];
        }
    }
}

// -------------------------------------------------------------------------
// k_convert: fp32 -> bf16 copies into ws (no-op if inputs already bf16).
// -------------------------------------------------------------------------
__global__ void k_convert(void* ws,
                          const void* a0, const void* a1, const void* a2, const void* a3,
                          const void* a4, const void* a5, const void* a6, const void* a7,
                          const void* a8, const void* a9, const void* a10, const void* a11,
                          const void* a12, const void* a13, const void* a14, const void* a15,
                          const void* a16, const void* a17) {
    if (*(const int*)((const char*)ws + WS_FLAG) == 0) return;
    const void* orig[18] = {a0,a1,a2,a3,a4,a5,a6,a7,a8,a9,a10,a11,a12,a13,a14,a15,a16,a17};
    u16* base = (u16*)((char*)ws + WS_COPY);
    const int gtid = blockIdx.x * blockDim.x + threadIdx.x;
    const int gs   = gridDim.x * blockDim.x;
    long long cum = 0;
    for (int a = 0; a < 18; ++a) {
        const float* src = (const float*)orig[a];
        u16* dst = base + cum;
        const int n = G_SZ[a];
        for (int i = gtid; i < n; i += gs) dst[i] = f2b(src[i]);
        cum += n;
    }
}

// -------------------------------------------------------------------------
// k_lens
// -------------------------------------------------------------------------
__global__ void k_lens(const int* __restrict__ d_ids, const int* __restrict__ utt_len,
                       void* ws) {
    int* lens = (int*)((char*)ws + WS_LENS);
    int n = blockIdx.x * blockDim.x + threadIdx.x;
    if (n < NUTT) {
        int b = n >> 5;
        int u = n & (UU - 1);
        int L = utt_len[d_ids[b] * UU + u];
        lens[n] = min(max(L, 1), TLEN);
    }
}

// -------------------------------------------------------------------------
// k_fwd: forward GRU scan. 16 utt/block, 512 thr (8 waves). Gate-tiles per
// wave are columns {j, 128+j, 256+j} for j = wv*16+mm -> gates in registers.
// Writes o_f bf16 to ws.
// -------------------------------------------------------------------------
__global__ __launch_bounds__(512)
void k_fwd(const int* __restrict__ x, void* ws) {
    const u16* const* tab = (const u16* const*)((char*)ws + WS_TAB);
    const u16* emb  = tab[0];
    const u16* w_ih = tab[1];
    const u16* w_hh = tab[2];
    const u16* b_ih = tab[3];
    const u16* b_hh = tab[4];
    u16* of = (u16*)((char*)ws + WS_OF);

    const int n0 = blockIdx.x * NBU;
    __shared__ __align__(16) u16 sh_hi[16 * 136];
    __shared__ __align__(16) u16 sh_lo[16 * 136];

    const int tid = threadIdx.x, lane = tid & 63, wvi = tid >> 6;
    const int q4 = lane >> 4, mm = lane & 15;
    const int j = wvi * 16 + mm;

    for (int i = tid; i < 16 * 136; i += 512) { sh_hi[i] = 0; sh_lo[i] = 0; }

    bf16x8 wih[3][8]; bf16x8 whh[3][4]; float bx[3], bg[3];
#pragma unroll
    for (int n3 = 0; n3 < 3; ++n3) {
        const int g = n3 * HDIM + j;
#pragma unroll
        for (int ks = 0; ks < 8; ++ks)
            wih[n3][ks] = *(const bf16x8*)(w_ih + g * EDIM + ks * 32 + q4 * 8);
#pragma unroll
        for (int ks = 0; ks < 4; ++ks)
            whh[n3][ks] = *(const bf16x8*)(w_hh + g * HDIM + ks * 32 + q4 * 8);
        bx[n3] = b2f(b_ih[g]); bg[n3] = b2f(b_hh[g]);
    }
    float hprev[4] = {0.f, 0.f, 0.f, 0.f};
    __syncthreads();

    for (int t = 0; t < TLEN; ++t) {
        const int tok = x[(n0 + mm) * TLEN + t];
        const u16* arow = emb + (size_t)tok * EDIM;
        f32x4 accx[3], accg[3];
#pragma unroll
        for (int n3 = 0; n3 < 3; ++n3) {
            accx[n3] = (f32x4){bx[n3], bx[n3], bx[n3], bx[n3]};
            accg[n3] = (f32x4){bg[n3], bg[n3], bg[n3], bg[n3]};
        }
#pragma unroll
        for (int ks = 0; ks < 8; ++ks) {
            bf16x8 a = *(const bf16x8*)(arow + ks * 32 + q4 * 8);
#pragma unroll
            for (int n3 = 0; n3 < 3; ++n3) accx[n3] = MFMA16(a, wih[n3][ks], accx[n3]);
        }
#pragma unroll
        for (int ks = 0; ks < 4; ++ks) {
            bf16x8 ahi = *(const bf16x8*)(sh_hi + mm * 136 + ks * 32 + q4 * 8);
            bf16x8 alo = *(const bf16x8*)(sh_lo + mm * 136 + ks * 32 + q4 * 8);
#pragma unroll
            for (int n3 = 0; n3 < 3; ++n3) {
                accg[n3] = MFMA16(ahi, whh[n3][ks], accg[n3]);
                accg[n3] = MFMA16(alo, whh[n3][ks], accg[n3]);
            }
        }
        __syncthreads();   // all hi/lo reads of step t done
#pragma unroll
        for (int rr = 0; rr < 4; ++rr) {
            const int u = q4 * 4 + rr;
            const float r  = fsigmoid(accx[0][rr] + accg[0][rr]);
            const float z  = fsigmoid(accx[1][rr] + accg[1][rr]);
            const float nn = ftanh(accx[2][rr] + r * accg[2][rr]);
            const float hn = (1.0f - z) * nn + z * hprev[rr];
            hprev[rr] = hn;
            const u16 hb = f2b(hn);
            sh_hi[u * 136 + j] = hb;
            sh_lo[u * 136 + j] = f2b(hn - b2f(hb));
            of[((size_t)(n0 + u) * TLEN + t) * HDIM + j] = hb;
        }
        __syncthreads();   // hi/lo ready for step t+1
    }
}

// -------------------------------------------------------------------------
// k_bwd_attn: backward GRU scan + online-softmax single-query attention +
// Wv/Wo/Wl epilogue. Same scan structure as k_fwd.
// -------------------------------------------------------------------------
__global__ __launch_bounds__(512)
void k_bwd_attn(const int* __restrict__ x, void* ws, void* outv) {
    const u16* const* tab = (const u16* const*)((char*)ws + WS_TAB);
    const u16* emb  = tab[0];
    const u16* w_ih = tab[5];
    const u16* w_hh = tab[6];
    const u16* b_ih = tab[7];
    const u16* b_hh = tab[8];
    const u16* wq = tab[9];  const u16* bq = tab[10];
    const u16* wk = tab[11];
    const u16* wv = tab[12]; const u16* bv = tab[13];
    const u16* wo = tab[14]; const u16* bo = tab[15];
    const u16* wl = tab[16]; const u16* bl = tab[17];
    const int* lens = (const int*)((char*)ws + WS_LENS);
    const u16* of = (const u16*)((char*)ws + WS_OF);
    const int flag = *(const int*)((const char*)ws + WS_FLAG);

    const int n0 = blockIdx.x * NBU;
    __shared__ __align__(16) u16 sh_hi[16 * 136];
    __shared__ __align__(16) u16 sh_lo[16 * 136];
    __shared__ float sh_hT[16 * 256];    // [u][e]: e<128 = o_f[tout], e>=128 = h_bwd
    __shared__ float sh_q[16 * 256];
    __shared__ float sh_uv[16 * 256];
    __shared__ float sh_acc[16 * 256];
    __shared__ int   sh_L[16];
    __shared__ float sh_m[16], sh_s[16], sh_scale[16], sh_w[16];

    const int tid = threadIdx.x, lane = tid & 63, wvi = tid >> 6;
    const int q4 = lane >> 4, mm = lane & 15;
    const int j = wvi * 16 + mm;

    for (int i = tid; i < 16 * 136; i += 512) { sh_hi[i] = 0; sh_lo[i] = 0; }
    for (int i = tid; i < 16 * 256; i += 512) sh_acc[i] = 0.0f;
    if (tid < 16) { sh_L[tid] = lens[n0 + tid]; sh_m[tid] = -1e30f; sh_s[tid] = 0.0f; }

    bf16x8 wih[3][8]; bf16x8 whh[3][4]; float bx[3], bg[3];
#pragma unroll
    for (int n3 = 0; n3 < 3; ++n3) {
        const int g = n3 * HDIM + j;
#pragma unroll
        for (int ks = 0; ks < 8; ++ks)
            wih[n3][ks] = *(const bf16x8*)(w_ih + g * EDIM + ks * 32 + q4 * 8);
#pragma unroll
        for (int ks = 0; ks < 4; ++ks)
            whh[n3][ks] = *(const bf16x8*)(w_hh + g * HDIM + ks * 32 + q4 * 8);
        bx[n3] = b2f(b_ih[g]); bg[n3] = b2f(b_hh[g]);
    }
    float hprev[4] = {0.f, 0.f, 0.f, 0.f};
    __syncthreads();

    for (int t = 0; t < TLEN; ++t) {
        // ---- phase A: MFMA + gates (reads sh_hi/lo of step t-1)
        const int te = max(sh_L[mm] - 1 - t, 0);
        const int tok = x[(n0 + mm) * TLEN + te];
        const u16* arow = emb + (size_t)tok * EDIM;
        f32x4 accx[3], accg[3];
#pragma unroll
        for (int n3 = 0; n3 < 3; ++n3) {
            accx[n3] = (f32x4){bx[n3], bx[n3], bx[n3], bx[n3]};
            accg[n3] = (f32x4){bg[n3], bg[n3], bg[n3], bg[n3]};
        }
#pragma unroll
        for (int ks = 0; ks < 8; ++ks) {
            bf16x8 a = *(const bf16x8*)(arow + ks * 32 + q4 * 8);
#pragma unroll
            for (int n3 = 0; n3 < 3; ++n3) accx[n3] = MFMA16(a, wih[n3][ks], accx[n3]);
        }
#pragma unroll
        for (int ks = 0; ks < 4; ++ks) {
            bf16x8 ahi = *(const bf16x8*)(sh_hi + mm * 136 + ks * 32 + q4 * 8);
            bf16x8 alo = *(const bf16x8*)(sh_lo + mm * 136 + ks * 32 + q4 * 8);
#pragma unroll
            for (int n3 = 0; n3 < 3; ++n3) {
                accg[n3] = MFMA16(ahi, whh[n3][ks], accg[n3]);
                accg[n3] = MFMA16(alo, whh[n3][ks], accg[n3]);
            }
        }
        float hnv[4];
#pragma unroll
        for (int rr = 0; rr < 4; ++rr) {
            const float r  = fsigmoid(accx[0][rr] + accg[0][rr]);
            const float z  = fsigmoid(accx[1][rr] + accg[1][rr]);
            const float nn = ftanh(accx[2][rr] + r * accg[2][rr]);
            hnv[rr] = (1.0f - z) * nn + z * hprev[rr];
            hprev[rr] = hnv[rr];
        }
        __syncthreads();   // B1: hi/lo reads done

        // ---- phase B: publish state + assemble h_t
#pragma unroll
        for (int rr = 0; rr < 4; ++rr) {
            const int u = q4 * 4 + rr;
            const float hn = hnv[rr];
            const u16 hb = f2b(hn);
            sh_hi[u * 136 + j] = hb;
            sh_lo[u * 136 + j] = f2b(hn - b2f(hb));
            sh_hT[u * 256 + 128 + j] = hn;
            const int tout = sh_L[u] - 1 - t;
            sh_hT[u * 256 + j] = (tout >= 0)
                ? b2f(of[((size_t)(n0 + u) * TLEN + tout) * HDIM + j]) : 0.0f;
        }
        __syncthreads();   // B2: hT ready

        // ---- t==0: q = Wq h_last + bq ; uv = Wk^T q
        if (t == 0) {
            for (int r8 = 0; r8 < 8; ++r8) {
                const int flat = r8 * 512 + tid;
                const int u = flat >> 8, i = flat & 255;
                float s = b2f(bq[i]);
                const u16* wr = wq + i * EDIM;
                for (int e = 0; e < EDIM; ++e) s += b2f(wr[e]) * sh_hT[u * 256 + e];
                sh_q[u * 256 + i] = s;
            }
            __syncthreads();
            for (int r8 = 0; r8 < 8; ++r8) {
                const int flat = r8 * 512 + tid;
                const int u = flat >> 8, e = flat & 255;
                float s = 0.0f;
                for (int i2 = 0; i2 < EDIM; ++i2) s += b2f(wk[i2 * EDIM + e]) * sh_q[u * 256 + i2];
                sh_uv[u * 256 + e] = s;
            }
            __syncthreads();
        }

        // ---- phase C: score + online softmax (32 lanes per utterance)
        {
            const int u = tid >> 5, l = tid & 31;
            float p = 0.0f;
#pragma unroll
            for (int d = 0; d < 8; ++d) {
                const int e = l * 8 + d;
                p += sh_hT[u * 256 + e] * sh_uv[u * 256 + e];
            }
#pragma unroll
            for (int o = 16; o > 0; o >>= 1) p += __shfl_xor(p, o, 32);
            if (l == 0) {
                if (sh_L[u] - 1 - t >= 0) {
                    const float sc = p * 0.0625f;
                    const float mo = sh_m[u];
                    const float mn = fmaxf(mo, sc);
                    const float scl = __expf(mo - mn);
                    const float w   = __expf(sc - mn);
                    sh_s[u] = sh_s[u] * scl + w;
                    sh_m[u] = mn;
                    sh_scale[u] = scl;
                    sh_w[u] = w;
                } else {
                    sh_scale[u] = 1.0f;
                    sh_w[u] = 0.0f;
                }
            }
        }
        __syncthreads();   // B3: scale/w ready

        // ---- phase D: acc = acc*scale + w*h
        for (int r8 = 0; r8 < 8; ++r8) {
            const int flat = r8 * 512 + tid;
            const int u = flat >> 8, e = flat & 255;
            sh_acc[u * 256 + e] = sh_acc[u * 256 + e] * sh_scale[u] + sh_w[u] * sh_hT[u * 256 + e];
        }
        // no barrier needed here: next phase-A touches only hi/lo; B1 protects hT
    }
    __syncthreads();

    // ---- epilogue
    for (int r8 = 0; r8 < 8; ++r8) {
        const int flat = r8 * 512 + tid;
        const int u = flat >> 8, e = flat & 255;
        sh_hT[u * 256 + e] = sh_acc[u * 256 + e] / sh_s[u];
    }
    __syncthreads();
    for (int r8 = 0; r8 < 8; ++r8) {
        const int flat = r8 * 512 + tid;
        const int u = flat >> 8, i = flat & 255;
        float s = b2f(bv[i]);
        const u16* wr = wv + i * EDIM;
        for (int e = 0; e < EDIM; ++e) s += b2f(wr[e]) * sh_hT[u * 256 + e];
        sh_q[u * 256 + i] = s;
    }
    __syncthreads();
    for (int r8 = 0; r8 < 8; ++r8) {
        const int flat = r8 * 512 + tid;
        const int u = flat >> 8, i = flat & 255;
        float s = b2f(bo[i]);
        const u16* wr = wo + i * EDIM;
        for (int e = 0; e < EDIM; ++e) s += b2f(wr[e]) * sh_q[u * 256 + e];
        sh_uv[u * 256 + i] = s;
    }
    __syncthreads();
    for (int r8 = 0; r8 < 8; ++r8) {
        const int flat = r8 * 512 + tid;
        const int u = flat >> 8, i = flat & 255;
        float s = b2f(bl[i]);
        const u16* wr = wl + i * EDIM;
        for (int e = 0; e < EDIM; ++e) s += b2f(wr[e]) * sh_uv[u * 256 + e];
        const size_t oidx = (size_t)(n0 + u) * EDIM + i;
        if (flag) ((float*)outv)[oidx] = s;      // fp32 dataset
        else      ((u16*)outv)[oidx]   = f2b(s); // bf16 dataset
    }
}

// -------------------------------------------------------------------------
extern "C" void kernel_launch(void* const* d_in, const int* in_sizes, int n_in,
                              void* d_out, int out_size, void* d_ws, size_t ws_size,
                              hipStream_t stream) {
    const int* x       = (const int*)d_in[0];
    const int* d_ids   = (const int*)d_in[1];
    const int* utt_len = (const int*)d_in[2];
    // float arrays (dtype resolved on device): indices 3..21, skipping 15 (bk,
    // softmax-invariant and zero).
    const void* f_arr[18] = {
        d_in[3],                       // emb
        d_in[4], d_in[5], d_in[6], d_in[7],    // w_ih_f, w_hh_f, b_ih_f, b_hh_f
        d_in[8], d_in[9], d_in[10], d_in[11],  // w_ih_b, w_hh_b, b_ih_b, b_hh_b
        d_in[12], d_in[13],            // wq, bq
        d_in[14],                      // wk
        d_in[16], d_in[17],            // wv, bv
        d_in[18], d_in[19],            // wo, bo
        d_in[20], d_in[21]             // wl, bl
    };

    k_detect<<<1, 64, 0, stream>>>(d_ws,
        f_arr[0], f_arr[1], f_arr[2], f_arr[3], f_arr[4], f_arr[5], f_arr[6], f_arr[7],
        f_arr[8], f_arr[9], f_arr[10], f_arr[11], f_arr[12], f_arr[13], f_arr[14],
        f_arr[15], f_arr[16], f_arr[17]);

    k_convert<<<256, 256, 0, stream>>>(d_ws,
        f_arr[0], f_arr[1], f_arr[2], f_arr[3], f_arr[4], f_arr[5], f_arr[6], f_arr[7],
        f_arr[8], f_arr[9], f_arr[10], f_arr[11], f_arr[12], f_arr[13], f_arr[14],
        f_arr[15], f_arr[16], f_arr[17]);

    k_lens<<<4, 256, 0, stream>>>(d_ids, utt_len, d_ws);

    k_fwd<<<NUTT / NBU, 512, 0, stream>>>(x, d_ws);

    k_bwd_attn<<<NUTT / NBU, 512, 0, stream>>>(x, d_ws, d_out);
}

// Round 4
// 1238.135 us; speedup vs baseline: 1.7841x; 1.7841x over previous
//
#include <hip/hip_runtime.h>
#include <math.h>
#include <stdint.h>

typedef unsigned short u16;
typedef unsigned int   u32;
typedef __attribute__((ext_vector_type(8))) short bf16x8;
typedef __attribute__((ext_vector_type(4))) float f32x4;

#define EDIM 256
#define HDIM 128
#define TLEN 128
#define NUTT 1024
#define UU   32
#define NBU  16

// workspace layout (bytes)
#define WS_FLAG 0
#define WS_LENS 64
#define WS_TAB  4608
#define WS_COPY 8192            // bf16 copies of the 18 float arrays (16.6 MB)
#define WS_OF   18874368LL      // o_f bf16 [NUTT][TLEN][HDIM] (33.55 MB)
#define WS_OB   52428800LL      // o_b bf16 [NUTT][TLEN][HDIM] (33.55 MB) -> end 86 MB

#define MFMA16(a, b, c) __builtin_amdgcn_mfma_f32_16x16x32_bf16((a), (b), (c), 0, 0, 0)

__constant__ int G_SZ[18] = {7680000, 98304, 49152, 384, 384, 98304, 49152, 384, 384,
                             65536, 256, 65536, 65536, 256, 65536, 256, 65536, 256};

__device__ __forceinline__ float b2f(u16 b) {
    u32 u = ((u32)b) << 16; float f; __builtin_memcpy(&f, &u, 4); return f;
}
__device__ __forceinline__ u16 f2b(float f) {   // RNE, finite inputs only
    u32 u; __builtin_memcpy(&u, &f, 4);
    u32 r = u + 0x7FFFu + ((u >> 16) & 1u);
    return (u16)(r >> 16);
}
__device__ __forceinline__ float fsigmoid(float x) { return 1.0f / (1.0f + __expf(-x)); }
__device__ __forceinline__ float ftanh(float x) { return 1.0f - 2.0f / (__expf(2.0f * x) + 1.0f); }

// -------------------------------------------------------------------------
// k_detect: decide bf16 vs fp32 by scanning emb bits; build pointer table.
// -------------------------------------------------------------------------
__global__ void k_detect(void* ws,
                         const void* a0, const void* a1, const void* a2, const void* a3,
                         const void* a4, const void* a5, const void* a6, const void* a7,
                         const void* a8, const void* a9, const void* a10, const void* a11,
                         const void* a12, const void* a13, const void* a14, const void* a15,
                         const void* a16, const void* a17) {
    const u16* p = (const u16*)a0;
    int cnt = 0;
    for (int i = threadIdx.x; i < 65536; i += 64)
        cnt += ((p[i] & 0x7F80) == 0x7F80) ? 1 : 0;
#pragma unroll
    for (int o = 32; o > 0; o >>= 1) cnt += __shfl_down(cnt, o);
    if (threadIdx.x == 0) {
        const void* orig[18] = {a0,a1,a2,a3,a4,a5,a6,a7,a8,a9,a10,a11,a12,a13,a14,a15,a16,a17};
        const int flag = (cnt > 0) ? 1 : 0;
        *(int*)((char*)ws + WS_FLAG) = flag;
        const u16** tab = (const u16**)((char*)ws + WS_TAB);
        char* base = (char*)ws + WS_COPY;
        long long cum = 0;
        for (int a = 0; a < 18; ++a) {
            tab[a] = flag ? (const u16*)(base + cum * 2) : (const u16*)orig[a];
            cum += G_SZ[a];
        }
    }
}

// -------------------------------------------------------------------------
// k_convert: fp32 -> bf16 copies into ws, float4-vectorized (all sizes %4==0).
// -------------------------------------------------------------------------
__global__ void k_convert(void* ws,
                          const void* a0, const void* a1, const void* a2, const void* a3,
                          const void* a4, const void* a5, const void* a6, const void* a7,
                          const void* a8, const void* a9, const void* a10, const void* a11,
                          const void* a12, const void* a13, const void* a14, const void* a15,
                          const void* a16, const void* a17) {
    if (*(const int*)((const char*)ws + WS_FLAG) == 0) return;
    const void* orig[18] = {a0,a1,a2,a3,a4,a5,a6,a7,a8,a9,a10,a11,a12,a13,a14,a15,a16,a17};
    u16* base = (u16*)((char*)ws + WS_COPY);
    const int gtid = blockIdx.x * blockDim.x + threadIdx.x;
    const int gs   = gridDim.x * blockDim.x;
    long long cum = 0;
    for (int a = 0; a < 18; ++a) {
        const float4* src = (const float4*)orig[a];
        uint2* dst = (uint2*)(base + cum);
        const int n4 = G_SZ[a] >> 2;
        for (int i = gtid; i < n4; i += gs) {
            float4 v = src[i];
            uint2 pk;
            pk.x = (u32)f2b(v.x) | ((u32)f2b(v.y) << 16);
            pk.y = (u32)f2b(v.z) | ((u32)f2b(v.w) << 16);
            dst[i] = pk;
        }
        cum += G_SZ[a];
    }
}

// -------------------------------------------------------------------------
// k_lens
// -------------------------------------------------------------------------
__global__ void k_lens(const int* __restrict__ d_ids, const int* __restrict__ utt_len,
                       void* ws) {
    int* lens = (int*)((char*)ws + WS_LENS);
    int n = blockIdx.x * blockDim.x + threadIdx.x;
    if (n < NUTT) {
        int b = n >> 5;
        int u = n & (UU - 1);
        int L = utt_len[d_ids[b] * UU + u];
        lens[n] = min(max(L, 1), TLEN);
    }
}

// -------------------------------------------------------------------------
// k_scan: GRU scan, both directions (blockIdx.y). 16 utt/block, 512 thr.
// Single barrier/step (double-buffered hi/lo LDS state); tokens in LDS;
// embedding A-fragment prefetched one step ahead in registers.
// Writes o_f / o_b as bf16 to ws.
// -------------------------------------------------------------------------
__global__ __launch_bounds__(512, 2)
void k_scan(const int* __restrict__ x, void* ws) {
    const u16* const* tab = (const u16* const*)((char*)ws + WS_TAB);
    const int dir = blockIdx.y;
    const u16* emb  = tab[0];
    const u16* w_ih = tab[1 + dir * 4];
    const u16* w_hh = tab[2 + dir * 4];
    const u16* b_ih = tab[3 + dir * 4];
    const u16* b_hh = tab[4 + dir * 4];
    u16* outp = (u16*)((char*)ws + (dir ? WS_OB : WS_OF));
    const int* lens = (const int*)((char*)ws + WS_LENS);

    const int n0 = blockIdx.x * NBU;
    __shared__ __align__(16) u16 sh_hi[2][16 * 136];
    __shared__ __align__(16) u16 sh_lo[2][16 * 136];
    __shared__ int sh_tok[16 * 128];
    __shared__ int sh_L[16];

    const int tid = threadIdx.x, lane = tid & 63, wvi = tid >> 6;
    const int q4 = lane >> 4, mm = lane & 15;
    const int j = wvi * 16 + mm;

    for (int i = tid; i < 16 * 136; i += 512) { sh_hi[0][i] = 0; sh_lo[0][i] = 0; }
    for (int i = tid; i < 16 * 128; i += 512) {
        const int u = i >> 7, tt = i & 127;
        sh_tok[i] = x[(n0 + u) * TLEN + tt];
    }
    if (tid < 16) sh_L[tid] = lens[n0 + tid];

    bf16x8 wih[3][8]; bf16x8 whh[3][4]; float bx[3], bg[3];
#pragma unroll
    for (int n3 = 0; n3 < 3; ++n3) {
        const int g = n3 * HDIM + j;
#pragma unroll
        for (int ks = 0; ks < 8; ++ks)
            wih[n3][ks] = *(const bf16x8*)(w_ih + g * EDIM + ks * 32 + q4 * 8);
#pragma unroll
        for (int ks = 0; ks < 4; ++ks)
            whh[n3][ks] = *(const bf16x8*)(w_hh + g * HDIM + ks * 32 + q4 * 8);
        bx[n3] = b2f(b_ih[g]); bg[n3] = b2f(b_hh[g]);
    }
    float hprev[4] = {0.f, 0.f, 0.f, 0.f};
    __syncthreads();   // sh_tok / sh_L / sh_hi[0] ready

    const int L_mm = sh_L[mm];
    // prefetch A-fragment for t=0
    bf16x8 af[2][8];
    {
        const int te0 = dir ? (L_mm - 1) : 0;   // L>=1
        const u16* ar = emb + (size_t)sh_tok[mm * 128 + te0] * EDIM;
#pragma unroll
        for (int ks = 0; ks < 8; ++ks) af[0][ks] = *(const bf16x8*)(ar + ks * 32 + q4 * 8);
    }

    for (int t = 0; t < TLEN; ++t) {
        const int cur = t & 1, nxt = cur ^ 1;
        // issue next step's A-fragment loads early (off the critical chain)
        if (t + 1 < TLEN) {
            const int te = dir ? max(L_mm - 2 - t, 0) : (t + 1);
            const u16* ar = emb + (size_t)sh_tok[mm * 128 + te] * EDIM;
#pragma unroll
            for (int ks = 0; ks < 8; ++ks) af[nxt][ks] = *(const bf16x8*)(ar + ks * 32 + q4 * 8);
        }

        f32x4 accx[3], accg[3];
#pragma unroll
        for (int n3 = 0; n3 < 3; ++n3) {
            accx[n3] = (f32x4){bx[n3], bx[n3], bx[n3], bx[n3]};
            accg[n3] = (f32x4){bg[n3], bg[n3], bg[n3], bg[n3]};
        }
#pragma unroll
        for (int ks = 0; ks < 8; ++ks) {
#pragma unroll
            for (int n3 = 0; n3 < 3; ++n3) accx[n3] = MFMA16(af[cur][ks], wih[n3][ks], accx[n3]);
        }
#pragma unroll
        for (int ks = 0; ks < 4; ++ks) {
            bf16x8 ahi = *(const bf16x8*)(sh_hi[cur] + mm * 136 + ks * 32 + q4 * 8);
            bf16x8 alo = *(const bf16x8*)(sh_lo[cur] + mm * 136 + ks * 32 + q4 * 8);
#pragma unroll
            for (int n3 = 0; n3 < 3; ++n3) {
                accg[n3] = MFMA16(ahi, whh[n3][ks], accg[n3]);
                accg[n3] = MFMA16(alo, whh[n3][ks], accg[n3]);
            }
        }
#pragma unroll
        for (int rr = 0; rr < 4; ++rr) {
            const int u = q4 * 4 + rr;
            const float r  = fsigmoid(accx[0][rr] + accg[0][rr]);
            const float z  = fsigmoid(accx[1][rr] + accg[1][rr]);
            const float nn = ftanh(accx[2][rr] + r * accg[2][rr]);
            const float hn = (1.0f - z) * nn + z * hprev[rr];
            hprev[rr] = hn;
            const u16 hb = f2b(hn);
            sh_hi[nxt][u * 136 + j] = hb;              // write OTHER buffer: no
            sh_lo[nxt][u * 136 + j] = f2b(hn - b2f(hb)); // read/write hazard
            const int tout = dir ? (sh_L[u] - 1 - t) : t;
            if (tout >= 0)
                outp[((size_t)(n0 + u) * TLEN + tout) * HDIM + j] = hb;
        }
        __syncthreads();   // single barrier per step
    }
}

// -------------------------------------------------------------------------
// k_attn: per-utterance attention + epilogue. 1024 blocks x 256 threads.
// h[t] = [o_f[t], o_b[t]] (bf16 in ws). q = Wq h[L-1]+bq; uv = Wk^T q;
// score_t = h_t.uv/16; softmax; ctx_w = sum w_t h_t; out = Wl(Wo(Wv ctx_w
// + bv) + bo) + bl.
// -------------------------------------------------------------------------
__global__ __launch_bounds__(256)
void k_attn(void* ws, void* outv) {
    const u16* const* tab = (const u16* const*)((char*)ws + WS_TAB);
    const u16* wq = tab[9];  const u16* bq = tab[10];
    const u16* wk = tab[11];
    const u16* wv = tab[12]; const u16* bv = tab[13];
    const u16* wo = tab[14]; const u16* bo = tab[15];
    const u16* wl = tab[16]; const u16* bl = tab[17];
    const int* lens = (const int*)((char*)ws + WS_LENS);
    const int flag = *(const int*)((const char*)ws + WS_FLAG);

    const int n = blockIdx.x;
    const int L = lens[n];
    const u16* hf = (const u16*)((char*)ws + WS_OF) + (size_t)n * TLEN * HDIM;
    const u16* hb = (const u16*)((char*)ws + WS_OB) + (size_t)n * TLEN * HDIM;

    __shared__ float sh_hl[EDIM];     // h_last, then ctx_w
    __shared__ float sh_v1[EDIM];     // q, then Wo out
    __shared__ float sh_uv[EDIM];     // Wk^T q, then Wv out
    __shared__ float sh_sc[TLEN];     // scores -> exp weights
    __shared__ float sh_part[4 * EDIM];
    __shared__ float sh_sum;

    const int tid = threadIdx.x, lane = tid & 63, wid = tid >> 6;

    // h_last
    sh_hl[tid] = (tid < HDIM) ? b2f(hf[(size_t)(L - 1) * HDIM + tid])
                              : b2f(hb[(size_t)(L - 1) * HDIM + (tid - HDIM)]);
    __syncthreads();

    // q[i] = Wq[i,:].h_last + bq[i]
    {
        float s = b2f(bq[tid]);
        const u16* wr = wq + tid * EDIM;
        for (int ks = 0; ks < 32; ++ks) {
            bf16x8 w8 = *(const bf16x8*)(wr + ks * 8);
#pragma unroll
            for (int d = 0; d < 8; ++d) s += b2f((u16)w8[d]) * sh_hl[ks * 8 + d];
        }
        sh_v1[tid] = s;
    }
    __syncthreads();

    // uv[e] = sum_i Wk[i,e] * q[i]  (lane-coalesced column reads)
    {
        float s = 0.0f;
        for (int i = 0; i < EDIM; ++i) s += b2f(wk[i * EDIM + tid]) * sh_v1[i];
        sh_uv[tid] = s;
    }
    __syncthreads();

    // scores: one wave per row; lane covers 4 dims (fwd half lanes 0-31, bwd 32-63)
    for (int t = wid; t < L; t += 4) {
        const u16* src = (lane < 32) ? (hf + (size_t)t * HDIM + lane * 4)
                                     : (hb + (size_t)t * HDIM + (lane - 32) * 4);
        const int e0 = lane * 4;
        float p = b2f(src[0]) * sh_uv[e0]     + b2f(src[1]) * sh_uv[e0 + 1] +
                  b2f(src[2]) * sh_uv[e0 + 2] + b2f(src[3]) * sh_uv[e0 + 3];
#pragma unroll
        for (int o = 32; o > 0; o >>= 1) p += __shfl_xor(p, o);
        if (lane == 0) sh_sc[t] = p * 0.0625f;   // / sqrt(256)
    }
    __syncthreads();

    // softmax over t<L (wave 0)
    if (wid == 0) {
        float v0 = (lane < L) ? sh_sc[lane] : -INFINITY;
        float v1 = (lane + 64 < L) ? sh_sc[lane + 64] : -INFINITY;
        float m = fmaxf(v0, v1);
#pragma unroll
        for (int o = 32; o > 0; o >>= 1) m = fmaxf(m, __shfl_xor(m, o));
        float e0 = (lane < L) ? __expf(v0 - m) : 0.0f;
        float e1 = (lane + 64 < L) ? __expf(v1 - m) : 0.0f;
        float ss = e0 + e1;
#pragma unroll
        for (int o = 32; o > 0; o >>= 1) ss += __shfl_xor(ss, o);
        sh_sc[lane] = e0;
        sh_sc[lane + 64] = e1;
        if (lane == 0) sh_sum = ss;
    }
    __syncthreads();

    // weighted sum of h rows (coalesced): each wave does t = wid, wid+4, ...
    {
        float acc0 = 0.f, acc1 = 0.f, acc2 = 0.f, acc3 = 0.f;
        for (int t = wid; t < L; t += 4) {
            const u16* src = (lane < 32) ? (hf + (size_t)t * HDIM + lane * 4)
                                         : (hb + (size_t)t * HDIM + (lane - 32) * 4);
            const float w = sh_sc[t];
            acc0 += w * b2f(src[0]); acc1 += w * b2f(src[1]);
            acc2 += w * b2f(src[2]); acc3 += w * b2f(src[3]);
        }
        const int e0 = lane * 4;
        sh_part[wid * EDIM + e0]     = acc0;
        sh_part[wid * EDIM + e0 + 1] = acc1;
        sh_part[wid * EDIM + e0 + 2] = acc2;
        sh_part[wid * EDIM + e0 + 3] = acc3;
    }
    __syncthreads();

    // ctx_w[e] = (sum of 4 wave partials) / sum
    {
        const float inv = 1.0f / sh_sum;
        sh_hl[tid] = (sh_part[tid] + sh_part[EDIM + tid] +
                      sh_part[2 * EDIM + tid] + sh_part[3 * EDIM + tid]) * inv;
    }
    __syncthreads();

    // Wv
    {
        float s = b2f(bv[tid]);
        const u16* wr = wv + tid * EDIM;
        for (int ks = 0; ks < 32; ++ks) {
            bf16x8 w8 = *(const bf16x8*)(wr + ks * 8);
#pragma unroll
            for (int d = 0; d < 8; ++d) s += b2f((u16)w8[d]) * sh_hl[ks * 8 + d];
        }
        sh_uv[tid] = s;
    }
    __syncthreads();

    // Wo
    {
        float s = b2f(bo[tid]);
        const u16* wr = wo + tid * EDIM;
        for (int ks = 0; ks < 32; ++ks) {
            bf16x8 w8 = *(const bf16x8*)(wr + ks * 8);
#pragma unroll
            for (int d = 0; d < 8; ++d) s += b2f((u16)w8[d]) * sh_uv[ks * 8 + d];
        }
        sh_v1[tid] = s;
    }
    __syncthreads();

    // Wl -> out
    {
        float s = b2f(bl[tid]);
        const u16* wr = wl + tid * EDIM;
        for (int ks = 0; ks < 32; ++ks) {
            bf16x8 w8 = *(const bf16x8*)(wr + ks * 8);
#pragma unroll
            for (int d = 0; d < 8; ++d) s += b2f((u16)w8[d]) * sh_v1[ks * 8 + d];
        }
        const size_t oidx = (size_t)n * EDIM + tid;
        if (flag) ((float*)outv)[oidx] = s;
        else      ((u16*)outv)[oidx]   = f2b(s);
    }
}

// -------------------------------------------------------------------------
extern "C" void kernel_launch(void* const* d_in, const int* in_sizes, int n_in,
                              void* d_out, int out_size, void* d_ws, size_t ws_size,
                              hipStream_t stream) {
    const int* x       = (const int*)d_in[0];
    const int* d_ids   = (const int*)d_in[1];
    const int* utt_len = (const int*)d_in[2];
    const void* f_arr[18] = {
        d_in[3],
        d_in[4], d_in[5], d_in[6], d_in[7],
        d_in[8], d_in[9], d_in[10], d_in[11],
        d_in[12], d_in[13],
        d_in[14],
        d_in[16], d_in[17],
        d_in[18], d_in[19],
        d_in[20], d_in[21]
    };

    k_detect<<<1, 64, 0, stream>>>(d_ws,
        f_arr[0], f_arr[1], f_arr[2], f_arr[3], f_arr[4], f_arr[5], f_arr[6], f_arr[7],
        f_arr[8], f_arr[9], f_arr[10], f_arr[11], f_arr[12], f_arr[13], f_arr[14],
        f_arr[15], f_arr[16], f_arr[17]);

    k_convert<<<1024, 256, 0, stream>>>(d_ws,
        f_arr[0], f_arr[1], f_arr[2], f_arr[3], f_arr[4], f_arr[5], f_arr[6], f_arr[7],
        f_arr[8], f_arr[9], f_arr[10], f_arr[11], f_arr[12], f_arr[13], f_arr[14],
        f_arr[15], f_arr[16], f_arr[17]);

    k_lens<<<4, 256, 0, stream>>>(d_ids, utt_len, d_ws);

    k_scan<<<dim3(NUTT / NBU, 2), 512, 0, stream>>>(x, d_ws);

    k_attn<<<NUTT, 256, 0, stream>>>(d_ws, d_out);
}

// Round 5
// 1185.620 us; speedup vs baseline: 1.8631x; 1.0443x over previous
//
#include <hip/hip_runtime.h>
#include <math.h>
#include <stdint.h>

typedef unsigned short u16;
typedef unsigned int   u32;
typedef __attribute__((ext_vector_type(8))) short bf16x8;
typedef __attribute__((ext_vector_type(4))) float f32x4;

#define EDIM 256
#define HDIM 128
#define TLEN 128
#define NUTT 1024
#define UU   32
#define NBU  8          // utterances per scan block (256 scan blocks total)

// workspace layout (bytes)
#define WS_FLAG 0
#define WS_LENS 64
#define WS_TAB  4608
#define WS_COPY 8192            // bf16 copies of the 18 float arrays (16.6 MB)
#define WS_OF   18874368LL      // o_f bf16 [NUTT][TLEN][HDIM] (33.55 MB)
#define WS_OB   52428800LL      // o_b bf16 [NUTT][TLEN][HDIM] (33.55 MB) -> end 86 MB

#define MFMA16(a, b, c) __builtin_amdgcn_mfma_f32_16x16x32_bf16((a), (b), (c), 0, 0, 0)

__constant__ int G_SZ[18] = {7680000, 98304, 49152, 384, 384, 98304, 49152, 384, 384,
                             65536, 256, 65536, 65536, 256, 65536, 256, 65536, 256};

__device__ __forceinline__ float b2f(u16 b) {
    u32 u = ((u32)b) << 16; float f; __builtin_memcpy(&f, &u, 4); return f;
}
__device__ __forceinline__ u16 f2b(float f) {   // RNE, finite inputs only
    u32 u; __builtin_memcpy(&u, &f, 4);
    u32 r = u + 0x7FFFu + ((u >> 16) & 1u);
    return (u16)(r >> 16);
}
__device__ __forceinline__ float fsigmoid(float x) { return 1.0f / (1.0f + __expf(-x)); }
__device__ __forceinline__ float ftanh(float x) { return 1.0f - 2.0f / (__expf(2.0f * x) + 1.0f); }

// -------------------------------------------------------------------------
// k_detect: decide bf16 vs fp32 by scanning emb bits; build pointer table.
// -------------------------------------------------------------------------
__global__ void k_detect(void* ws,
                         const void* a0, const void* a1, const void* a2, const void* a3,
                         const void* a4, const void* a5, const void* a6, const void* a7,
                         const void* a8, const void* a9, const void* a10, const void* a11,
                         const void* a12, const void* a13, const void* a14, const void* a15,
                         const void* a16, const void* a17) {
    const u16* p = (const u16*)a0;
    int cnt = 0;
    for (int i = threadIdx.x; i < 16384; i += 64)
        cnt += ((p[i] & 0x7F80) == 0x7F80) ? 1 : 0;
#pragma unroll
    for (int o = 32; o > 0; o >>= 1) cnt += __shfl_down(cnt, o);
    if (threadIdx.x == 0) {
        const void* orig[18] = {a0,a1,a2,a3,a4,a5,a6,a7,a8,a9,a10,a11,a12,a13,a14,a15,a16,a17};
        const int flag = (cnt > 0) ? 1 : 0;
        *(int*)((char*)ws + WS_FLAG) = flag;
        const u16** tab = (const u16**)((char*)ws + WS_TAB);
        char* base = (char*)ws + WS_COPY;
        long long cum = 0;
        for (int a = 0; a < 18; ++a) {
            tab[a] = flag ? (const u16*)(base + cum * 2) : (const u16*)orig[a];
            cum += G_SZ[a];
        }
    }
}

// -------------------------------------------------------------------------
// k_convert: fp32 -> bf16 copies into ws, float4-vectorized (all sizes %4==0).
// -------------------------------------------------------------------------
__global__ void k_convert(void* ws,
                          const void* a0, const void* a1, const void* a2, const void* a3,
                          const void* a4, const void* a5, const void* a6, const void* a7,
                          const void* a8, const void* a9, const void* a10, const void* a11,
                          const void* a12, const void* a13, const void* a14, const void* a15,
                          const void* a16, const void* a17) {
    if (*(const int*)((const char*)ws + WS_FLAG) == 0) return;
    const void* orig[18] = {a0,a1,a2,a3,a4,a5,a6,a7,a8,a9,a10,a11,a12,a13,a14,a15,a16,a17};
    u16* base = (u16*)((char*)ws + WS_COPY);
    const int gtid = blockIdx.x * blockDim.x + threadIdx.x;
    const int gs   = gridDim.x * blockDim.x;
    long long cum = 0;
    for (int a = 0; a < 18; ++a) {
        const float4* src = (const float4*)orig[a];
        uint2* dst = (uint2*)(base + cum);
        const int n4 = G_SZ[a] >> 2;
        for (int i = gtid; i < n4; i += gs) {
            float4 v = src[i];
            uint2 pk;
            pk.x = (u32)f2b(v.x) | ((u32)f2b(v.y) << 16);
            pk.y = (u32)f2b(v.z) | ((u32)f2b(v.w) << 16);
            dst[i] = pk;
        }
        cum += G_SZ[a];
    }
}

// -------------------------------------------------------------------------
// k_lens
// -------------------------------------------------------------------------
__global__ void k_lens(const int* __restrict__ d_ids, const int* __restrict__ utt_len,
                       void* ws) {
    int* lens = (int*)((char*)ws + WS_LENS);
    int n = blockIdx.x * blockDim.x + threadIdx.x;
    if (n < NUTT) {
        int b = n >> 5;
        int u = n & (UU - 1);
        int L = utt_len[d_ids[b] * UU + u];
        lens[n] = min(max(L, 1), TLEN);
    }
}

// -------------------------------------------------------------------------
// k_scan: GRU scan, both directions (blockIdx.y). 8 utt/block, 512 thr,
// 256 blocks (all CUs). MFMA M-rows 8..15 duplicate rows 0..7 (latency-
// bound: free). Single barrier/step; double-buffered LDS h-state; emb
// A-fragment register-prefetched 1 step ahead; outputs staged in a
// double-buffered LDS tile and flushed every 8 steps with coalesced
// dwordx4 stores (kills the 10x partial-line write amplification).
// -------------------------------------------------------------------------
__global__ __launch_bounds__(512)
void k_scan(const int* __restrict__ x, void* ws) {
    const u16* const* tab = (const u16* const*)((char*)ws + WS_TAB);
    const int dir = blockIdx.y;
    const u16* emb  = tab[0];
    const u16* w_ih = tab[1 + dir * 4];
    const u16* w_hh = tab[2 + dir * 4];
    const u16* b_ih = tab[3 + dir * 4];
    const u16* b_hh = tab[4 + dir * 4];
    u16* outp = (u16*)((char*)ws + (dir ? WS_OB : WS_OF));
    const int* lens = (const int*)((char*)ws + WS_LENS);

    const int n0 = blockIdx.x * NBU;
    __shared__ __align__(16) u16 sh_hi[2][NBU * 136];
    __shared__ __align__(16) u16 sh_lo[2][NBU * 136];
    __shared__ __align__(16) u16 sh_out[2][NBU][8][HDIM];   // 2 x 16 KB staging
    __shared__ int sh_tok[NBU * TLEN];
    __shared__ int sh_L[NBU];

    const int tid = threadIdx.x, lane = tid & 63, wvi = tid >> 6;
    const int q4 = lane >> 4, mm = lane & 15;
    const int j = wvi * 16 + mm;
    const int u8 = mm & 7;          // A-row utterance (rows 8..15 duplicate)

    for (int i = tid; i < NBU * 136; i += 512) { sh_hi[0][i] = 0; sh_lo[0][i] = 0; }
    for (int i = tid; i < NBU * TLEN; i += 512) {
        const int u = i >> 7, tt = i & 127;
        sh_tok[i] = x[(n0 + u) * TLEN + tt];
    }
    if (tid < NBU) sh_L[tid] = lens[n0 + tid];

    bf16x8 wih[3][8]; bf16x8 whh[3][4]; float bx[3], bg[3];
#pragma unroll
    for (int n3 = 0; n3 < 3; ++n3) {
        const int g = n3 * HDIM + j;
#pragma unroll
        for (int ks = 0; ks < 8; ++ks)
            wih[n3][ks] = *(const bf16x8*)(w_ih + g * EDIM + ks * 32 + q4 * 8);
#pragma unroll
        for (int ks = 0; ks < 4; ++ks)
            whh[n3][ks] = *(const bf16x8*)(w_hh + g * HDIM + ks * 32 + q4 * 8);
        bx[n3] = b2f(b_ih[g]); bg[n3] = b2f(b_hh[g]);
    }
    float hprev[4] = {0.f, 0.f, 0.f, 0.f};
    __syncthreads();   // sh_tok / sh_L / sh_hi[0] ready

    const int L_u = sh_L[u8];
    bf16x8 af[2][8];
    {
        const int te0 = dir ? (L_u - 1) : 0;    // L>=1
        const u16* ar = emb + (size_t)sh_tok[u8 * TLEN + te0] * EDIM;
#pragma unroll
        for (int ks = 0; ks < 8; ++ks) af[0][ks] = *(const bf16x8*)(ar + ks * 32 + q4 * 8);
    }

    for (int t = 0; t < TLEN; ++t) {
        const int cur = t & 1, nxt = cur ^ 1;
        const int obuf = (t >> 3) & 1, slot = t & 7;

        // prefetch next step's A-fragment (issued early, off the chain)
        if (t + 1 < TLEN) {
            const int te = dir ? max(L_u - 2 - t, 0) : (t + 1);
            const u16* ar = emb + (size_t)sh_tok[u8 * TLEN + te] * EDIM;
#pragma unroll
            for (int ks = 0; ks < 8; ++ks) af[nxt][ks] = *(const bf16x8*)(ar + ks * 32 + q4 * 8);
        }

        f32x4 accx[3], accg[3];
#pragma unroll
        for (int n3 = 0; n3 < 3; ++n3) {
            accx[n3] = (f32x4){bx[n3], bx[n3], bx[n3], bx[n3]};
            accg[n3] = (f32x4){bg[n3], bg[n3], bg[n3], bg[n3]};
        }
#pragma unroll
        for (int ks = 0; ks < 8; ++ks) {
#pragma unroll
            for (int n3 = 0; n3 < 3; ++n3) accx[n3] = MFMA16(af[cur][ks], wih[n3][ks], accx[n3]);
        }
#pragma unroll
        for (int ks = 0; ks < 4; ++ks) {
            bf16x8 ahi = *(const bf16x8*)(sh_hi[cur] + u8 * 136 + ks * 32 + q4 * 8);
            bf16x8 alo = *(const bf16x8*)(sh_lo[cur] + u8 * 136 + ks * 32 + q4 * 8);
#pragma unroll
            for (int n3 = 0; n3 < 3; ++n3) {
                accg[n3] = MFMA16(ahi, whh[n3][ks], accg[n3]);
                accg[n3] = MFMA16(alo, whh[n3][ks], accg[n3]);
            }
        }
        if (q4 < 2) {   // D rows 0..7 = the real utterances
#pragma unroll
            for (int rr = 0; rr < 4; ++rr) {
                const int u = q4 * 4 + rr;
                const float r  = fsigmoid(accx[0][rr] + accg[0][rr]);
                const float z  = fsigmoid(accx[1][rr] + accg[1][rr]);
                const float nn = ftanh(accx[2][rr] + r * accg[2][rr]);
                const float hn = (1.0f - z) * nn + z * hprev[rr];
                hprev[rr] = hn;
                const u16 hb = f2b(hn);
                sh_hi[nxt][u * 136 + j] = hb;
                sh_lo[nxt][u * 136 + j] = f2b(hn - b2f(hb));
                sh_out[obuf][u][slot][j] = hb;
            }
        }
        __syncthreads();   // single barrier/step: publishes h-state + staging

        if (slot == 7) {
            // coalesced flush of 8 steps x 8 utt x 128 cols (16 KB)
            const int rowIdx = tid >> 3;        // 0..63
            const int part   = tid & 7;         // 0..7 (32 B each)
            const int fu = rowIdx >> 3, fs = rowIdx & 7;
            const int tt = (t & ~7) + fs;
            const int tout = dir ? (sh_L[fu] - 1 - tt) : tt;
            if (tout >= 0) {
                const u16* srcp = &sh_out[obuf][fu][fs][part * 16];
                uint4 v0 = *(const uint4*)(srcp);
                uint4 v1 = *(const uint4*)(srcp + 8);
                u16* dstp = outp + ((size_t)(n0 + fu) * TLEN + tout) * HDIM + part * 16;
                *(uint4*)(dstp)     = v0;
                *(uint4*)(dstp + 8) = v1;
            }
            // no extra barrier: next 8 steps write sh_out[obuf^1]
        }
    }
}

// -------------------------------------------------------------------------
// k_attn: per-utterance attention + epilogue. 1024 blocks x 256 threads.
// -------------------------------------------------------------------------
__global__ __launch_bounds__(256)
void k_attn(void* ws, void* outv) {
    const u16* const* tab = (const u16* const*)((char*)ws + WS_TAB);
    const u16* wq = tab[9];  const u16* bq = tab[10];
    const u16* wk = tab[11];
    const u16* wv = tab[12]; const u16* bv = tab[13];
    const u16* wo = tab[14]; const u16* bo = tab[15];
    const u16* wl = tab[16]; const u16* bl = tab[17];
    const int* lens = (const int*)((char*)ws + WS_LENS);
    const int flag = *(const int*)((const char*)ws + WS_FLAG);

    const int n = blockIdx.x;
    const int L = lens[n];
    const u16* hf = (const u16*)((char*)ws + WS_OF) + (size_t)n * TLEN * HDIM;
    const u16* hb = (const u16*)((char*)ws + WS_OB) + (size_t)n * TLEN * HDIM;

    __shared__ float sh_hl[EDIM];
    __shared__ float sh_v1[EDIM];
    __shared__ float sh_uv[EDIM];
    __shared__ float sh_sc[TLEN];
    __shared__ float sh_part[4 * EDIM];
    __shared__ float sh_sum;

    const int tid = threadIdx.x, lane = tid & 63, wid = tid >> 6;

    sh_hl[tid] = (tid < HDIM) ? b2f(hf[(size_t)(L - 1) * HDIM + tid])
                              : b2f(hb[(size_t)(L - 1) * HDIM + (tid - HDIM)]);
    __syncthreads();

    {   // q = Wq h_last + bq
        float s = b2f(bq[tid]);
        const u16* wr = wq + tid * EDIM;
        for (int ks = 0; ks < 32; ++ks) {
            bf16x8 w8 = *(const bf16x8*)(wr + ks * 8);
#pragma unroll
            for (int d = 0; d < 8; ++d) s += b2f((u16)w8[d]) * sh_hl[ks * 8 + d];
        }
        sh_v1[tid] = s;
    }
    __syncthreads();

    {   // uv = Wk^T q
        float s = 0.0f;
        for (int i = 0; i < EDIM; ++i) s += b2f(wk[i * EDIM + tid]) * sh_v1[i];
        sh_uv[tid] = s;
    }
    __syncthreads();

    for (int t = wid; t < L; t += 4) {
        const u16* src = (lane < 32) ? (hf + (size_t)t * HDIM + lane * 4)
                                     : (hb + (size_t)t * HDIM + (lane - 32) * 4);
        const int e0 = lane * 4;
        float p = b2f(src[0]) * sh_uv[e0]     + b2f(src[1]) * sh_uv[e0 + 1] +
                  b2f(src[2]) * sh_uv[e0 + 2] + b2f(src[3]) * sh_uv[e0 + 3];
#pragma unroll
        for (int o = 32; o > 0; o >>= 1) p += __shfl_xor(p, o);
        if (lane == 0) sh_sc[t] = p * 0.0625f;
    }
    __syncthreads();

    if (wid == 0) {
        float v0 = (lane < L) ? sh_sc[lane] : -INFINITY;
        float v1 = (lane + 64 < L) ? sh_sc[lane + 64] : -INFINITY;
        float m = fmaxf(v0, v1);
#pragma unroll
        for (int o = 32; o > 0; o >>= 1) m = fmaxf(m, __shfl_xor(m, o));
        float e0 = (lane < L) ? __expf(v0 - m) : 0.0f;
        float e1 = (lane + 64 < L) ? __expf(v1 - m) : 0.0f;
        float ss = e0 + e1;
#pragma unroll
        for (int o = 32; o > 0; o >>= 1) ss += __shfl_xor(ss, o);
        sh_sc[lane] = e0;
        sh_sc[lane + 64] = e1;
        if (lane == 0) sh_sum = ss;
    }
    __syncthreads();

    {
        float acc0 = 0.f, acc1 = 0.f, acc2 = 0.f, acc3 = 0.f;
        for (int t = wid; t < L; t += 4) {
            const u16* src = (lane < 32) ? (hf + (size_t)t * HDIM + lane * 4)
                                         : (hb + (size_t)t * HDIM + (lane - 32) * 4);
            const float w = sh_sc[t];
            acc0 += w * b2f(src[0]); acc1 += w * b2f(src[1]);
            acc2 += w * b2f(src[2]); acc3 += w * b2f(src[3]);
        }
        const int e0 = lane * 4;
        sh_part[wid * EDIM + e0]     = acc0;
        sh_part[wid * EDIM + e0 + 1] = acc1;
        sh_part[wid * EDIM + e0 + 2] = acc2;
        sh_part[wid * EDIM + e0 + 3] = acc3;
    }
    __syncthreads();

    {
        const float inv = 1.0f / sh_sum;
        sh_hl[tid] = (sh_part[tid] + sh_part[EDIM + tid] +
                      sh_part[2 * EDIM + tid] + sh_part[3 * EDIM + tid]) * inv;
    }
    __syncthreads();

    {   // Wv
        float s = b2f(bv[tid]);
        const u16* wr = wv + tid * EDIM;
        for (int ks = 0; ks < 32; ++ks) {
            bf16x8 w8 = *(const bf16x8*)(wr + ks * 8);
#pragma unroll
            for (int d = 0; d < 8; ++d) s += b2f((u16)w8[d]) * sh_hl[ks * 8 + d];
        }
        sh_uv[tid] = s;
    }
    __syncthreads();

    {   // Wo
        float s = b2f(bo[tid]);
        const u16* wr = wo + tid * EDIM;
        for (int ks = 0; ks < 32; ++ks) {
            bf16x8 w8 = *(const bf16x8*)(wr + ks * 8);
#pragma unroll
            for (int d = 0; d < 8; ++d) s += b2f((u16)w8[d]) * sh_uv[ks * 8 + d];
        }
        sh_v1[tid] = s;
    }
    __syncthreads();

    {   // Wl -> out
        float s = b2f(bl[tid]);
        const u16* wr = wl + tid * EDIM;
        for (int ks = 0; ks < 32; ++ks) {
            bf16x8 w8 = *(const bf16x8*)(wr + ks * 8);
#pragma unroll
            for (int d = 0; d < 8; ++d) s += b2f((u16)w8[d]) * sh_v1[ks * 8 + d];
        }
        const size_t oidx = (size_t)n * EDIM + tid;
        if (flag) ((float*)outv)[oidx] = s;
        else      ((u16*)outv)[oidx]   = f2b(s);
    }
}

// -------------------------------------------------------------------------
extern "C" void kernel_launch(void* const* d_in, const int* in_sizes, int n_in,
                              void* d_out, int out_size, void* d_ws, size_t ws_size,
                              hipStream_t stream) {
    const int* x       = (const int*)d_in[0];
    const int* d_ids   = (const int*)d_in[1];
    const int* utt_len = (const int*)d_in[2];
    const void* f_arr[18] = {
        d_in[3],
        d_in[4], d_in[5], d_in[6], d_in[7],
        d_in[8], d_in[9], d_in[10], d_in[11],
        d_in[12], d_in[13],
        d_in[14],
        d_in[16], d_in[17],
        d_in[18], d_in[19],
        d_in[20], d_in[21]
    };

    k_detect<<<1, 64, 0, stream>>>(d_ws,
        f_arr[0], f_arr[1], f_arr[2], f_arr[3], f_arr[4], f_arr[5], f_arr[6], f_arr[7],
        f_arr[8], f_arr[9], f_arr[10], f_arr[11], f_arr[12], f_arr[13], f_arr[14],
        f_arr[15], f_arr[16], f_arr[17]);

    k_convert<<<1024, 256, 0, stream>>>(d_ws,
        f_arr[0], f_arr[1], f_arr[2], f_arr[3], f_arr[4], f_arr[5], f_arr[6], f_arr[7],
        f_arr[8], f_arr[9], f_arr[10], f_arr[11], f_arr[12], f_arr[13], f_arr[14],
        f_arr[15], f_arr[16], f_arr[17]);

    k_lens<<<4, 256, 0, stream>>>(d_ids, utt_len, d_ws);

    k_scan<<<dim3(NUTT / NBU, 2), 512, 0, stream>>>(x, d_ws);

    k_attn<<<NUTT, 256, 0, stream>>>(d_ws, d_out);
}

// Round 6
// 496.241 us; speedup vs baseline: 4.4514x; 2.3892x over previous
//
#include <hip/hip_runtime.h>
#include <math.h>
#include <stdint.h>

typedef unsigned short u16;
typedef unsigned int   u32;
typedef __attribute__((ext_vector_type(8))) short bf16x8;
typedef __attribute__((ext_vector_type(4))) float f32x4;

#define EDIM 256
#define HDIM 128
#define TLEN 128
#define NUTT 1024
#define UU   32
#define NBU  8          // utterances per scan block (256 scan blocks total)

// workspace layout (bytes)
#define WS_FLAG 0
#define WS_LENS 64
#define WS_TAB  4608
#define WS_COPY 8192            // bf16 copies of the 18 float arrays (16.6 MB)
#define WS_OF   18874368LL      // o_f bf16 [NUTT][TLEN][HDIM] (33.55 MB)
#define WS_OB   52428800LL      // o_b bf16 [NUTT][TLEN][HDIM] (33.55 MB) -> end 86 MB

#define MFMA16(a, b, c) __builtin_amdgcn_mfma_f32_16x16x32_bf16((a), (b), (c), 0, 0, 0)

__constant__ int G_SZ[18] = {7680000, 98304, 49152, 384, 384, 98304, 49152, 384, 384,
                             65536, 256, 65536, 65536, 256, 65536, 256, 65536, 256};

__device__ __forceinline__ float b2f(u16 b) {
    u32 u = ((u32)b) << 16; float f; __builtin_memcpy(&f, &u, 4); return f;
}
__device__ __forceinline__ u16 f2b(float f) {   // RNE, finite inputs only
    u32 u; __builtin_memcpy(&u, &f, 4);
    u32 r = u + 0x7FFFu + ((u >> 16) & 1u);
    return (u16)(r >> 16);
}
__device__ __forceinline__ float fsigmoid(float x) { return 1.0f / (1.0f + __expf(-x)); }
__device__ __forceinline__ float ftanh(float x) { return 1.0f - 2.0f / (__expf(2.0f * x) + 1.0f); }

// -------------------------------------------------------------------------
// k_detect: decide bf16 vs fp32 by scanning emb bits; build pointer table.
// -------------------------------------------------------------------------
__global__ void k_detect(void* ws,
                         const void* a0, const void* a1, const void* a2, const void* a3,
                         const void* a4, const void* a5, const void* a6, const void* a7,
                         const void* a8, const void* a9, const void* a10, const void* a11,
                         const void* a12, const void* a13, const void* a14, const void* a15,
                         const void* a16, const void* a17) {
    const u16* p = (const u16*)a0;
    int cnt = 0;
    for (int i = threadIdx.x; i < 16384; i += 64)
        cnt += ((p[i] & 0x7F80) == 0x7F80) ? 1 : 0;
#pragma unroll
    for (int o = 32; o > 0; o >>= 1) cnt += __shfl_down(cnt, o);
    if (threadIdx.x == 0) {
        const void* orig[18] = {a0,a1,a2,a3,a4,a5,a6,a7,a8,a9,a10,a11,a12,a13,a14,a15,a16,a17};
        const int flag = (cnt > 0) ? 1 : 0;
        *(int*)((char*)ws + WS_FLAG) = flag;
        const u16** tab = (const u16**)((char*)ws + WS_TAB);
        char* base = (char*)ws + WS_COPY;
        long long cum = 0;
        for (int a = 0; a < 18; ++a) {
            tab[a] = flag ? (const u16*)(base + cum * 2) : (const u16*)orig[a];
            cum += G_SZ[a];
        }
    }
}

// -------------------------------------------------------------------------
// k_convert: fp32 -> bf16 copies into ws, float4-vectorized (all sizes %4==0).
// -------------------------------------------------------------------------
__global__ void k_convert(void* ws,
                          const void* a0, const void* a1, const void* a2, const void* a3,
                          const void* a4, const void* a5, const void* a6, const void* a7,
                          const void* a8, const void* a9, const void* a10, const void* a11,
                          const void* a12, const void* a13, const void* a14, const void* a15,
                          const void* a16, const void* a17) {
    if (*(const int*)((const char*)ws + WS_FLAG) == 0) return;
    const void* orig[18] = {a0,a1,a2,a3,a4,a5,a6,a7,a8,a9,a10,a11,a12,a13,a14,a15,a16,a17};
    u16* base = (u16*)((char*)ws + WS_COPY);
    const int gtid = blockIdx.x * blockDim.x + threadIdx.x;
    const int gs   = gridDim.x * blockDim.x;
    long long cum = 0;
    for (int a = 0; a < 18; ++a) {
        const float4* src = (const float4*)orig[a];
        uint2* dst = (uint2*)(base + cum);
        const int n4 = G_SZ[a] >> 2;
        for (int i = gtid; i < n4; i += gs) {
            float4 v = src[i];
            uint2 pk;
            pk.x = (u32)f2b(v.x) | ((u32)f2b(v.y) << 16);
            pk.y = (u32)f2b(v.z) | ((u32)f2b(v.w) << 16);
            dst[i] = pk;
        }
        cum += G_SZ[a];
    }
}

// -------------------------------------------------------------------------
// k_lens
// -------------------------------------------------------------------------
__global__ void k_lens(const int* __restrict__ d_ids, const int* __restrict__ utt_len,
                       void* ws) {
    int* lens = (int*)((char*)ws + WS_LENS);
    int n = blockIdx.x * blockDim.x + threadIdx.x;
    if (n < NUTT) {
        int b = n >> 5;
        int u = n & (UU - 1);
        int L = utt_len[d_ids[b] * UU + u];
        lens[n] = min(max(L, 1), TLEN);
    }
}

// -------------------------------------------------------------------------
// k_scan: GRU scan, both directions (blockIdx.y). 8 utt/block, 512 thr,
// 256 blocks = 1 block/CU. NO cross-iteration MFMA-typed register arrays
// (that spilled 2^31 B/dispatch to scratch in R4/R5). Emb rows are
// prefetched through LDS: waves 0-3 each load one uint4 (t+1's rows) at
// the TOP of step t and ds_write it at the END of step t -> global
// latency never sits on the recurrence chain, and no register buffer
// survives an iteration. Single barrier/step; double-buffered h-state
// and emb tiles; coalesced 8-step output flush.
// -------------------------------------------------------------------------
__global__ __launch_bounds__(512)
void k_scan(const int* __restrict__ x, void* ws) {
    const u16* const* tab = (const u16* const*)((char*)ws + WS_TAB);
    const int dir = blockIdx.y;
    const u16* emb  = tab[0];
    const u16* w_ih = tab[1 + dir * 4];
    const u16* w_hh = tab[2 + dir * 4];
    const u16* b_ih = tab[3 + dir * 4];
    const u16* b_hh = tab[4 + dir * 4];
    u16* outp = (u16*)((char*)ws + (dir ? WS_OB : WS_OF));
    const int* lens = (const int*)((char*)ws + WS_LENS);

    const int n0 = blockIdx.x * NBU;
    __shared__ __align__(16) u16 sh_emb[2][NBU][264];       // 8.4 KB, stride-padded
    __shared__ __align__(16) u16 sh_hi[2][NBU * 136];
    __shared__ __align__(16) u16 sh_lo[2][NBU * 136];
    __shared__ __align__(16) u16 sh_out[2][NBU][8][HDIM];   // 2 x 16 KB staging
    __shared__ int sh_tok[NBU * TLEN];
    __shared__ int sh_L[NBU];

    const int tid = threadIdx.x, lane = tid & 63, wvi = tid >> 6;
    const int q4 = lane >> 4, mm = lane & 15;
    const int j = wvi * 16 + mm;
    const int u8 = mm & 7;              // A-row utterance (rows 8..15 duplicate)

    for (int i = tid; i < NBU * 136; i += 512) { sh_hi[0][i] = 0; sh_lo[0][i] = 0; }
    for (int i = tid; i < NBU * TLEN; i += 512) {
        const int u = i >> 7, tt = i & 127;
        sh_tok[i] = x[(n0 + u) * TLEN + tt];
    }
    if (tid < NBU) sh_L[tid] = lens[n0 + tid];

    bf16x8 wih[3][8]; bf16x8 whh[3][4]; float bx[3], bg[3];
#pragma unroll
    for (int n3 = 0; n3 < 3; ++n3) {
        const int g = n3 * HDIM + j;
#pragma unroll
        for (int ks = 0; ks < 8; ++ks)
            wih[n3][ks] = *(const bf16x8*)(w_ih + g * EDIM + ks * 32 + q4 * 8);
#pragma unroll
        for (int ks = 0; ks < 4; ++ks)
            whh[n3][ks] = *(const bf16x8*)(w_hh + g * HDIM + ks * 32 + q4 * 8);
        bx[n3] = b2f(b_ih[g]); bg[n3] = b2f(b_hh[g]);
    }
    float hprev[4] = {0.f, 0.f, 0.f, 0.f};
    __syncthreads();   // sh_tok / sh_L / sh_hi[0] ready

    // prefetch lane roles (waves 0..3): lane covers chunk c of utterance u
    const bool pwave = (wvi < 4);
    const int pf_u = lane & 7;
    const int pf_c = wvi * 8 + (lane >> 3);     // 0..31 (16B chunks of a 512B row)
    const int pf_L = sh_L[pf_u];
    const int L_u8 = sh_L[u8];
    (void)L_u8;

    uint4 pf;
    if (pwave) {   // stage t=0 rows synchronously (one-time latency)
        const int te0 = dir ? (pf_L - 1) : 0;
        const int tok = sh_tok[pf_u * TLEN + te0];
        pf = *(const uint4*)(emb + (size_t)tok * EDIM + pf_c * 8);
        *(uint4*)&sh_emb[0][pf_u][pf_c * 8] = pf;
    }
    __syncthreads();   // sh_emb[0] ready

    for (int t = 0; t < TLEN; ++t) {
        const int cur = t & 1, nxt = cur ^ 1;
        const int obuf = (t >> 3) & 1, slot = t & 7;

        // issue next step's row loads NOW (committed to LDS at end of step)
        if (pwave && (t + 1 < TLEN)) {
            const int te = dir ? max(pf_L - 2 - t, 0) : (t + 1);
            const int tok = sh_tok[pf_u * TLEN + te];
            pf = *(const uint4*)(emb + (size_t)tok * EDIM + pf_c * 8);
        }

        f32x4 accx[3], accg[3];
#pragma unroll
        for (int n3 = 0; n3 < 3; ++n3) {
            accx[n3] = (f32x4){bx[n3], bx[n3], bx[n3], bx[n3]};
            accg[n3] = (f32x4){bg[n3], bg[n3], bg[n3], bg[n3]};
        }
#pragma unroll
        for (int ks = 0; ks < 8; ++ks) {
            bf16x8 a = *(const bf16x8*)&sh_emb[cur][u8][ks * 32 + q4 * 8];
#pragma unroll
            for (int n3 = 0; n3 < 3; ++n3) accx[n3] = MFMA16(a, wih[n3][ks], accx[n3]);
        }
#pragma unroll
        for (int ks = 0; ks < 4; ++ks) {
            bf16x8 ahi = *(const bf16x8*)(sh_hi[cur] + u8 * 136 + ks * 32 + q4 * 8);
            bf16x8 alo = *(const bf16x8*)(sh_lo[cur] + u8 * 136 + ks * 32 + q4 * 8);
#pragma unroll
            for (int n3 = 0; n3 < 3; ++n3) {
                accg[n3] = MFMA16(ahi, whh[n3][ks], accg[n3]);
                accg[n3] = MFMA16(alo, whh[n3][ks], accg[n3]);
            }
        }
        if (q4 < 2) {   // D rows 0..7 = the real utterances
#pragma unroll
            for (int rr = 0; rr < 4; ++rr) {
                const int u = q4 * 4 + rr;
                const float r  = fsigmoid(accx[0][rr] + accg[0][rr]);
                const float z  = fsigmoid(accx[1][rr] + accg[1][rr]);
                const float nn = ftanh(accx[2][rr] + r * accg[2][rr]);
                const float hn = (1.0f - z) * nn + z * hprev[rr];
                hprev[rr] = hn;
                const u16 hb = f2b(hn);
                sh_hi[nxt][u * 136 + j] = hb;
                sh_lo[nxt][u * 136 + j] = f2b(hn - b2f(hb));
                sh_out[obuf][u][slot][j] = hb;
            }
        }

        // commit the prefetched rows (vmcnt wait lands here, a full step
        // after issue -> latency hidden)
        if (pwave && (t + 1 < TLEN))
            *(uint4*)&sh_emb[nxt][pf_u][pf_c * 8] = pf;

        __syncthreads();   // single barrier/step

        if (slot == 7) {
            // coalesced flush of 8 steps x 8 utt x 128 cols (16 KB)
            const int rowIdx = tid >> 3;        // 0..63
            const int part   = tid & 7;         // 0..7 (32 B each)
            const int fu = rowIdx >> 3, fs = rowIdx & 7;
            const int tt = (t & ~7) + fs;
            const int tout = dir ? (sh_L[fu] - 1 - tt) : tt;
            if (tout >= 0) {
                const u16* srcp = &sh_out[obuf][fu][fs][part * 16];
                uint4 v0 = *(const uint4*)(srcp);
                uint4 v1 = *(const uint4*)(srcp + 8);
                u16* dstp = outp + ((size_t)(n0 + fu) * TLEN + tout) * HDIM + part * 16;
                *(uint4*)(dstp)     = v0;
                *(uint4*)(dstp + 8) = v1;
            }
            // no extra barrier: next 8 steps write sh_out[obuf^1]
        }
    }
}

// -------------------------------------------------------------------------
// k_attn: per-utterance attention + epilogue. 1024 blocks x 256 threads.
// -------------------------------------------------------------------------
__global__ __launch_bounds__(256)
void k_attn(void* ws, void* outv) {
    const u16* const* tab = (const u16* const*)((char*)ws + WS_TAB);
    const u16* wq = tab[9];  const u16* bq = tab[10];
    const u16* wk = tab[11];
    const u16* wv = tab[12]; const u16* bv = tab[13];
    const u16* wo = tab[14]; const u16* bo = tab[15];
    const u16* wl = tab[16]; const u16* bl = tab[17];
    const int* lens = (const int*)((char*)ws + WS_LENS);
    const int flag = *(const int*)((const char*)ws + WS_FLAG);

    const int n = blockIdx.x;
    const int L = lens[n];
    const u16* hf = (const u16*)((char*)ws + WS_OF) + (size_t)n * TLEN * HDIM;
    const u16* hb = (const u16*)((char*)ws + WS_OB) + (size_t)n * TLEN * HDIM;

    __shared__ float sh_hl[EDIM];
    __shared__ float sh_v1[EDIM];
    __shared__ float sh_uv[EDIM];
    __shared__ float sh_sc[TLEN];
    __shared__ float sh_part[4 * EDIM];
    __shared__ float sh_sum;

    const int tid = threadIdx.x, lane = tid & 63, wid = tid >> 6;

    sh_hl[tid] = (tid < HDIM) ? b2f(hf[(size_t)(L - 1) * HDIM + tid])
                              : b2f(hb[(size_t)(L - 1) * HDIM + (tid - HDIM)]);
    __syncthreads();

    {   // q = Wq h_last + bq
        float s = b2f(bq[tid]);
        const u16* wr = wq + tid * EDIM;
        for (int ks = 0; ks < 32; ++ks) {
            bf16x8 w8 = *(const bf16x8*)(wr + ks * 8);
#pragma unroll
            for (int d = 0; d < 8; ++d) s += b2f((u16)w8[d]) * sh_hl[ks * 8 + d];
        }
        sh_v1[tid] = s;
    }
    __syncthreads();

    {   // uv = Wk^T q
        float s = 0.0f;
        for (int i = 0; i < EDIM; ++i) s += b2f(wk[i * EDIM + tid]) * sh_v1[i];
        sh_uv[tid] = s;
    }
    __syncthreads();

    for (int t = wid; t < L; t += 4) {
        const u16* src = (lane < 32) ? (hf + (size_t)t * HDIM + lane * 4)
                                     : (hb + (size_t)t * HDIM + (lane - 32) * 4);
        const int e0 = lane * 4;
        float p = b2f(src[0]) * sh_uv[e0]     + b2f(src[1]) * sh_uv[e0 + 1] +
                  b2f(src[2]) * sh_uv[e0 + 2] + b2f(src[3]) * sh_uv[e0 + 3];
#pragma unroll
        for (int o = 32; o > 0; o >>= 1) p += __shfl_xor(p, o);
        if (lane == 0) sh_sc[t] = p * 0.0625f;
    }
    __syncthreads();

    if (wid == 0) {
        float v0 = (lane < L) ? sh_sc[lane] : -INFINITY;
        float v1 = (lane + 64 < L) ? sh_sc[lane + 64] : -INFINITY;
        float m = fmaxf(v0, v1);
#pragma unroll
        for (int o = 32; o > 0; o >>= 1) m = fmaxf(m, __shfl_xor(m, o));
        float e0 = (lane < L) ? __expf(v0 - m) : 0.0f;
        float e1 = (lane + 64 < L) ? __expf(v1 - m) : 0.0f;
        float ss = e0 + e1;
#pragma unroll
        for (int o = 32; o > 0; o >>= 1) ss += __shfl_xor(ss, o);
        sh_sc[lane] = e0;
        sh_sc[lane + 64] = e1;
        if (lane == 0) sh_sum = ss;
    }
    __syncthreads();

    {
        float acc0 = 0.f, acc1 = 0.f, acc2 = 0.f, acc3 = 0.f;
        for (int t = wid; t < L; t += 4) {
            const u16* src = (lane < 32) ? (hf + (size_t)t * HDIM + lane * 4)
                                         : (hb + (size_t)t * HDIM + (lane - 32) * 4);
            const float w = sh_sc[t];
            acc0 += w * b2f(src[0]); acc1 += w * b2f(src[1]);
            acc2 += w * b2f(src[2]); acc3 += w * b2f(src[3]);
        }
        const int e0 = lane * 4;
        sh_part[wid * EDIM + e0]     = acc0;
        sh_part[wid * EDIM + e0 + 1] = acc1;
        sh_part[wid * EDIM + e0 + 2] = acc2;
        sh_part[wid * EDIM + e0 + 3] = acc3;
    }
    __syncthreads();

    {
        const float inv = 1.0f / sh_sum;
        sh_hl[tid] = (sh_part[tid] + sh_part[EDIM + tid] +
                      sh_part[2 * EDIM + tid] + sh_part[3 * EDIM + tid]) * inv;
    }
    __syncthreads();

    {   // Wv
        float s = b2f(bv[tid]);
        const u16* wr = wv + tid * EDIM;
        for (int ks = 0; ks < 32; ++ks) {
            bf16x8 w8 = *(const bf16x8*)(wr + ks * 8);
#pragma unroll
            for (int d = 0; d < 8; ++d) s += b2f((u16)w8[d]) * sh_hl[ks * 8 + d];
        }
        sh_uv[tid] = s;
    }
    __syncthreads();

    {   // Wo
        float s = b2f(bo[tid]);
        const u16* wr = wo + tid * EDIM;
        for (int ks = 0; ks < 32; ++ks) {
            bf16x8 w8 = *(const bf16x8*)(wr + ks * 8);
#pragma unroll
            for (int d = 0; d < 8; ++d) s += b2f((u16)w8[d]) * sh_uv[ks * 8 + d];
        }
        sh_v1[tid] = s;
    }
    __syncthreads();

    {   // Wl -> out
        float s = b2f(bl[tid]);
        const u16* wr = wl + tid * EDIM;
        for (int ks = 0; ks < 32; ++ks) {
            bf16x8 w8 = *(const bf16x8*)(wr + ks * 8);
#pragma unroll
            for (int d = 0; d < 8; ++d) s += b2f((u16)w8[d]) * sh_v1[ks * 8 + d];
        }
        const size_t oidx = (size_t)n * EDIM + tid;
        if (flag) ((float*)outv)[oidx] = s;
        else      ((u16*)outv)[oidx]   = f2b(s);
    }
}

// -------------------------------------------------------------------------
extern "C" void kernel_launch(void* const* d_in, const int* in_sizes, int n_in,
                              void* d_out, int out_size, void* d_ws, size_t ws_size,
                              hipStream_t stream) {
    const int* x       = (const int*)d_in[0];
    const int* d_ids   = (const int*)d_in[1];
    const int* utt_len = (const int*)d_in[2];
    const void* f_arr[18] = {
        d_in[3],
        d_in[4], d_in[5], d_in[6], d_in[7],
        d_in[8], d_in[9], d_in[10], d_in[11],
        d_in[12], d_in[13],
        d_in[14],
        d_in[16], d_in[17],
        d_in[18], d_in[19],
        d_in[20], d_in[21]
    };

    k_detect<<<1, 64, 0, stream>>>(d_ws,
        f_arr[0], f_arr[1], f_arr[2], f_arr[3], f_arr[4], f_arr[5], f_arr[6], f_arr[7],
        f_arr[8], f_arr[9], f_arr[10], f_arr[11], f_arr[12], f_arr[13], f_arr[14],
        f_arr[15], f_arr[16], f_arr[17]);

    k_convert<<<1024, 256, 0, stream>>>(d_ws,
        f_arr[0], f_arr[1], f_arr[2], f_arr[3], f_arr[4], f_arr[5], f_arr[6], f_arr[7],
        f_arr[8], f_arr[9], f_arr[10], f_arr[11], f_arr[12], f_arr[13], f_arr[14],
        f_arr[15], f_arr[16], f_arr[17]);

    k_lens<<<4, 256, 0, stream>>>(d_ids, utt_len, d_ws);

    k_scan<<<dim3(NUTT / NBU, 2), 512, 0, stream>>>(x, d_ws);

    k_attn<<<NUTT, 256, 0, stream>>>(d_ws, d_out);
}

// Round 7
// 442.545 us; speedup vs baseline: 4.9915x; 1.1213x over previous
//
#include <hip/hip_runtime.h>
#include <math.h>
#include <stdint.h>

typedef unsigned short u16;
typedef unsigned int   u32;
typedef __attribute__((ext_vector_type(8))) short bf16x8;
typedef __attribute__((ext_vector_type(4))) float f32x4;

#define EDIM 256
#define HDIM 128
#define TLEN 128
#define NUTT 1024
#define UU   32
#define NBU  8          // utterances per scan block (256 scan blocks total)

// workspace layout (bytes)
#define WS_FLAG 0
#define WS_LENS 64
#define WS_TAB  4608
#define WS_COPY 8192            // bf16 copies of the 18 float arrays (16.6 MB)
#define WS_OF   18874368LL      // o_f bf16 [NUTT][TLEN][HDIM] (33.55 MB)
#define WS_OB   52428800LL      // o_b bf16 [NUTT][TLEN][HDIM] (33.55 MB) -> end 86 MB

#define MFMA16(a, b, c) __builtin_amdgcn_mfma_f32_16x16x32_bf16((a), (b), (c), 0, 0, 0)

// sh_out padded strides: slot stride 136 u16 (68 dw = 4 mod 32), utt stride
// 1096 u16 (548 dw = 4 mod 32) -> staging writes and flush reads are
// minimum-round bank accesses.
#define SOUT(u, s, j) ((u) * 1096 + (s) * 136 + (j))

__constant__ int G_SZ[18] = {7680000, 98304, 49152, 384, 384, 98304, 49152, 384, 384,
                             65536, 256, 65536, 65536, 256, 65536, 256, 65536, 256};

__device__ __forceinline__ float b2f(u16 b) {
    u32 u = ((u32)b) << 16; float f; __builtin_memcpy(&f, &u, 4); return f;
}
__device__ __forceinline__ u16 f2b(float f) {   // RNE, finite inputs only
    u32 u; __builtin_memcpy(&u, &f, 4);
    u32 r = u + 0x7FFFu + ((u >> 16) & 1u);
    return (u16)(r >> 16);
}
__device__ __forceinline__ float fsigmoid(float x) { return 1.0f / (1.0f + __expf(-x)); }
__device__ __forceinline__ float ftanh(float x) { return 1.0f - 2.0f / (__expf(2.0f * x) + 1.0f); }

// -------------------------------------------------------------------------
// k_detect: decide bf16 vs fp32 by scanning emb bits; build pointer table;
// also computes lens[] (merged former k_lens).
// -------------------------------------------------------------------------
__global__ void k_detect(void* ws,
                         const int* __restrict__ d_ids, const int* __restrict__ utt_len,
                         const void* a0, const void* a1, const void* a2, const void* a3,
                         const void* a4, const void* a5, const void* a6, const void* a7,
                         const void* a8, const void* a9, const void* a10, const void* a11,
                         const void* a12, const void* a13, const void* a14, const void* a15,
                         const void* a16, const void* a17) {
    const u16* p = (const u16*)a0;
    int cnt = 0;
    for (int i = threadIdx.x; i < 16384; i += 64)
        cnt += ((p[i] & 0x7F80) == 0x7F80) ? 1 : 0;
#pragma unroll
    for (int o = 32; o > 0; o >>= 1) cnt += __shfl_down(cnt, o);
    if (threadIdx.x == 0) {
        const void* orig[18] = {a0,a1,a2,a3,a4,a5,a6,a7,a8,a9,a10,a11,a12,a13,a14,a15,a16,a17};
        const int flag = (cnt > 0) ? 1 : 0;
        *(int*)((char*)ws + WS_FLAG) = flag;
        const u16** tab = (const u16**)((char*)ws + WS_TAB);
        char* base = (char*)ws + WS_COPY;
        long long cum = 0;
        for (int a = 0; a < 18; ++a) {
            tab[a] = flag ? (const u16*)(base + cum * 2) : (const u16*)orig[a];
            cum += G_SZ[a];
        }
    }
    // lens (no dependency on flag/tab)
    int* lens = (int*)((char*)ws + WS_LENS);
    for (int n = threadIdx.x; n < NUTT; n += 64) {
        int b = n >> 5;
        int u = n & (UU - 1);
        int L = utt_len[d_ids[b] * UU + u];
        lens[n] = min(max(L, 1), TLEN);
    }
}

// -------------------------------------------------------------------------
// k_convert: fp32 -> bf16 copies into ws (no-op if inputs already bf16).
// -------------------------------------------------------------------------
__global__ void k_convert(void* ws,
                          const void* a0, const void* a1, const void* a2, const void* a3,
                          const void* a4, const void* a5, const void* a6, const void* a7,
                          const void* a8, const void* a9, const void* a10, const void* a11,
                          const void* a12, const void* a13, const void* a14, const void* a15,
                          const void* a16, const void* a17) {
    if (*(const int*)((const char*)ws + WS_FLAG) == 0) return;
    const void* orig[18] = {a0,a1,a2,a3,a4,a5,a6,a7,a8,a9,a10,a11,a12,a13,a14,a15,a16,a17};
    u16* base = (u16*)((char*)ws + WS_COPY);
    const int gtid = blockIdx.x * blockDim.x + threadIdx.x;
    const int gs   = gridDim.x * blockDim.x;
    long long cum = 0;
    for (int a = 0; a < 18; ++a) {
        const float4* src = (const float4*)orig[a];
        uint2* dst = (uint2*)(base + cum);
        const int n4 = G_SZ[a] >> 2;
        for (int i = gtid; i < n4; i += gs) {
            float4 v = src[i];
            uint2 pk;
            pk.x = (u32)f2b(v.x) | ((u32)f2b(v.y) << 16);
            pk.y = (u32)f2b(v.z) | ((u32)f2b(v.w) << 16);
            dst[i] = pk;
        }
        cum += G_SZ[a];
    }
}

// -------------------------------------------------------------------------
// k_scan: GRU scan, both directions (blockIdx.y). 8 utt/block, 512 thr,
// 256 blocks = 1/CU. MFMA D rows 8..15 duplicate rows 0..7; quads 2,3 use
// their duplicate accumulators so EVERY lane does gate math for 2 rows
// (was: half the lanes doing 4 -> 2x gate-VALU issue width). Emb rows
// prefetched through LDS (no cross-iteration MFMA-register buffers -> no
// spill). Single barrier/step; padded sh_out staging flushed every 8 steps
// with coalesced dwordx4 stores.
// -------------------------------------------------------------------------
__global__ __launch_bounds__(512)
void k_scan(const int* __restrict__ x, void* ws) {
    const u16* const* tab = (const u16* const*)((char*)ws + WS_TAB);
    const int dir = blockIdx.y;
    const u16* emb  = tab[0];
    const u16* w_ih = tab[1 + dir * 4];
    const u16* w_hh = tab[2 + dir * 4];
    const u16* b_ih = tab[3 + dir * 4];
    const u16* b_hh = tab[4 + dir * 4];
    u16* outp = (u16*)((char*)ws + (dir ? WS_OB : WS_OF));
    const int* lens = (const int*)((char*)ws + WS_LENS);

    const int n0 = blockIdx.x * NBU;
    __shared__ __align__(16) u16 sh_emb[2][NBU][264];       // 8.4 KB
    __shared__ __align__(16) u16 sh_hi[2][NBU * 136];
    __shared__ __align__(16) u16 sh_lo[2][NBU * 136];
    __shared__ __align__(16) u16 sh_out[2][NBU * 1096];     // 35 KB, padded
    __shared__ int sh_tok[NBU * TLEN];
    __shared__ int sh_L[NBU];

    const int tid = threadIdx.x, lane = tid & 63, wvi = tid >> 6;
    const int q4 = lane >> 4, mm = lane & 15;
    const int j = wvi * 16 + mm;
    const int u8 = mm & 7;              // A-row utterance (rows 8..15 duplicate)

    for (int i = tid; i < NBU * 136; i += 512) { sh_hi[0][i] = 0; sh_lo[0][i] = 0; }
    for (int i = tid; i < NBU * TLEN; i += 512) {
        const int u = i >> 7, tt = i & 127;
        sh_tok[i] = x[(n0 + u) * TLEN + tt];
    }
    if (tid < NBU) sh_L[tid] = lens[n0 + tid];

    bf16x8 wih[3][8]; bf16x8 whh[3][4]; float bx[3], bg[3];
#pragma unroll
    for (int n3 = 0; n3 < 3; ++n3) {
        const int g = n3 * HDIM + j;
#pragma unroll
        for (int ks = 0; ks < 8; ++ks)
            wih[n3][ks] = *(const bf16x8*)(w_ih + g * EDIM + ks * 32 + q4 * 8);
#pragma unroll
        for (int ks = 0; ks < 4; ++ks)
            whh[n3][ks] = *(const bf16x8*)(w_hh + g * HDIM + ks * 32 + q4 * 8);
        bx[n3] = b2f(b_ih[g]); bg[n3] = b2f(b_hh[g]);
    }

    // gate-work assignment: lane handles acc rows arr = rr2 + (q4&2),
    // rr2 in {0,1}; utterance u = (q4*4 + arr) & 7. Covers all 8 utts
    // exactly once across the wave, all lanes busy.
    const int arr0 = (q4 & 2);          // acc index offset
    float hprev[2] = {0.f, 0.f};
    __syncthreads();   // sh_tok / sh_L / sh_hi[0] ready

    // prefetch lane roles (waves 0..3): lane covers chunk c of utterance u
    const bool pwave = (wvi < 4);
    const int pf_u = lane & 7;
    const int pf_c = wvi * 8 + (lane >> 3);     // 0..31 (16B chunks of a 512B row)
    const int pf_L = sh_L[pf_u];

    uint4 pf;
    if (pwave) {   // stage t=0 rows synchronously (one-time latency)
        const int te0 = dir ? (pf_L - 1) : 0;
        const int tok = sh_tok[pf_u * TLEN + te0];
        pf = *(const uint4*)(emb + (size_t)tok * EDIM + pf_c * 8);
        *(uint4*)&sh_emb[0][pf_u][pf_c * 8] = pf;
    }
    __syncthreads();   // sh_emb[0] ready

    for (int t = 0; t < TLEN; ++t) {
        const int cur = t & 1, nxt = cur ^ 1;
        const int obuf = (t >> 3) & 1, slot = t & 7;

        // issue next step's row loads NOW (committed to LDS at end of step)
        if (pwave && (t + 1 < TLEN)) {
            const int te = dir ? max(pf_L - 2 - t, 0) : (t + 1);
            const int tok = sh_tok[pf_u * TLEN + te];
            pf = *(const uint4*)(emb + (size_t)tok * EDIM + pf_c * 8);
        }

        f32x4 accx[3], accg[3];
#pragma unroll
        for (int n3 = 0; n3 < 3; ++n3) {
            accx[n3] = (f32x4){bx[n3], bx[n3], bx[n3], bx[n3]};
            accg[n3] = (f32x4){bg[n3], bg[n3], bg[n3], bg[n3]};
        }
#pragma unroll
        for (int ks = 0; ks < 8; ++ks) {
            bf16x8 a = *(const bf16x8*)&sh_emb[cur][u8][ks * 32 + q4 * 8];
#pragma unroll
            for (int n3 = 0; n3 < 3; ++n3) accx[n3] = MFMA16(a, wih[n3][ks], accx[n3]);
        }
#pragma unroll
        for (int ks = 0; ks < 4; ++ks) {
            bf16x8 ahi = *(const bf16x8*)(sh_hi[cur] + u8 * 136 + ks * 32 + q4 * 8);
            bf16x8 alo = *(const bf16x8*)(sh_lo[cur] + u8 * 136 + ks * 32 + q4 * 8);
#pragma unroll
            for (int n3 = 0; n3 < 3; ++n3) {
                accg[n3] = MFMA16(ahi, whh[n3][ks], accg[n3]);
                accg[n3] = MFMA16(alo, whh[n3][ks], accg[n3]);
            }
        }

        // ---- gate phase: every lane, 2 rows
#pragma unroll
        for (int rr2 = 0; rr2 < 2; ++rr2) {
            const int arr = rr2 + arr0;
            const int u   = (q4 * 4 + arr) & 7;
            const float r  = fsigmoid(accx[0][arr] + accg[0][arr]);
            const float z  = fsigmoid(accx[1][arr] + accg[1][arr]);
            const float nn = ftanh(accx[2][arr] + r * accg[2][arr]);
            const float hn = (1.0f - z) * nn + z * hprev[rr2];
            hprev[rr2] = hn;
            const u16 hb = f2b(hn);
            sh_hi[nxt][u * 136 + j] = hb;
            sh_lo[nxt][u * 136 + j] = f2b(hn - b2f(hb));
            sh_out[obuf][SOUT(u, slot, j)] = hb;
        }

        // commit the prefetched rows (vmcnt wait lands here, a full step
        // after issue -> latency hidden)
        if (pwave && (t + 1 < TLEN))
            *(uint4*)&sh_emb[nxt][pf_u][pf_c * 8] = pf;

        __syncthreads();   // single barrier/step

        if (slot == 7) {
            // coalesced flush of 8 steps x 8 utt x 128 cols (16 KB)
            const int rowIdx = tid >> 3;        // 0..63
            const int part   = tid & 7;         // 0..7 (32 B each)
            const int fu = rowIdx >> 3, fs = rowIdx & 7;
            const int tt = (t & ~7) + fs;
            const int tout = dir ? (sh_L[fu] - 1 - tt) : tt;
            if (tout >= 0) {
                const u16* srcp = &sh_out[obuf][SOUT(fu, fs, part * 16)];
                uint4 v0 = *(const uint4*)(srcp);
                uint4 v1 = *(const uint4*)(srcp + 8);
                u16* dstp = outp + ((size_t)(n0 + fu) * TLEN + tout) * HDIM + part * 16;
                *(uint4*)(dstp)     = v0;
                *(uint4*)(dstp + 8) = v1;
            }
            // no extra barrier: next 8 steps write sh_out[obuf^1]
        }
    }
}

// -------------------------------------------------------------------------
// k_attn: per-utterance attention + epilogue. 1024 blocks x 256 threads.
// Matvec FMA chains broken with dual accumulators; h-row loads via uint2.
// -------------------------------------------------------------------------
__global__ __launch_bounds__(256)
void k_attn(void* ws, void* outv) {
    const u16* const* tab = (const u16* const*)((char*)ws + WS_TAB);
    const u16* wq = tab[9];  const u16* bq = tab[10];
    const u16* wk = tab[11];
    const u16* wv = tab[12]; const u16* bv = tab[13];
    const u16* wo = tab[14]; const u16* bo = tab[15];
    const u16* wl = tab[16]; const u16* bl = tab[17];
    const int* lens = (const int*)((char*)ws + WS_LENS);
    const int flag = *(const int*)((const char*)ws + WS_FLAG);

    const int n = blockIdx.x;
    const int L = lens[n];
    const u16* hf = (const u16*)((char*)ws + WS_OF) + (size_t)n * TLEN * HDIM;
    const u16* hb = (const u16*)((char*)ws + WS_OB) + (size_t)n * TLEN * HDIM;

    __shared__ float sh_hl[EDIM];
    __shared__ float sh_v1[EDIM];
    __shared__ float sh_uv[EDIM];
    __shared__ float sh_sc[TLEN];
    __shared__ float sh_part[4 * EDIM];
    __shared__ float sh_sum;

    const int tid = threadIdx.x, lane = tid & 63, wid = tid >> 6;

    sh_hl[tid] = (tid < HDIM) ? b2f(hf[(size_t)(L - 1) * HDIM + tid])
                              : b2f(hb[(size_t)(L - 1) * HDIM + (tid - HDIM)]);
    __syncthreads();

    {   // q = Wq h_last + bq
        float s0 = b2f(bq[tid]), s1 = 0.0f;
        const u16* wr = wq + tid * EDIM;
#pragma unroll
        for (int ks = 0; ks < 32; ks += 2) {
            bf16x8 w8 = *(const bf16x8*)(wr + ks * 8);
            bf16x8 w9 = *(const bf16x8*)(wr + ks * 8 + 8);
#pragma unroll
            for (int d = 0; d < 8; ++d) {
                s0 += b2f((u16)w8[d]) * sh_hl[ks * 8 + d];
                s1 += b2f((u16)w9[d]) * sh_hl[ks * 8 + 8 + d];
            }
        }
        sh_v1[tid] = s0 + s1;
    }
    __syncthreads();

    {   // uv = Wk^T q
        float s0 = 0.0f, s1 = 0.0f;
        for (int i = 0; i < EDIM; i += 2) {
            s0 += b2f(wk[i * EDIM + tid]) * sh_v1[i];
            s1 += b2f(wk[(i + 1) * EDIM + tid]) * sh_v1[i + 1];
        }
        sh_uv[tid] = s0 + s1;
    }
    __syncthreads();

    for (int t = wid; t < L; t += 4) {
        const u16* src = (lane < 32) ? (hf + (size_t)t * HDIM + lane * 4)
                                     : (hb + (size_t)t * HDIM + (lane - 32) * 4);
        uint2 pv = *(const uint2*)src;
        const int e0 = lane * 4;
        float p = b2f((u16)(pv.x & 0xFFFF)) * sh_uv[e0]
                + b2f((u16)(pv.x >> 16))    * sh_uv[e0 + 1]
                + b2f((u16)(pv.y & 0xFFFF)) * sh_uv[e0 + 2]
                + b2f((u16)(pv.y >> 16))    * sh_uv[e0 + 3];
#pragma unroll
        for (int o = 32; o > 0; o >>= 1) p += __shfl_xor(p, o);
        if (lane == 0) sh_sc[t] = p * 0.0625f;
    }
    __syncthreads();

    if (wid == 0) {
        float v0 = (lane < L) ? sh_sc[lane] : -INFINITY;
        float v1 = (lane + 64 < L) ? sh_sc[lane + 64] : -INFINITY;
        float m = fmaxf(v0, v1);
#pragma unroll
        for (int o = 32; o > 0; o >>= 1) m = fmaxf(m, __shfl_xor(m, o));
        float e0 = (lane < L) ? __expf(v0 - m) : 0.0f;
        float e1 = (lane + 64 < L) ? __expf(v1 - m) : 0.0f;
        float ss = e0 + e1;
#pragma unroll
        for (int o = 32; o > 0; o >>= 1) ss += __shfl_xor(ss, o);
        sh_sc[lane] = e0;
        sh_sc[lane + 64] = e1;
        if (lane == 0) sh_sum = ss;
    }
    __syncthreads();

    {
        float acc0 = 0.f, acc1 = 0.f, acc2 = 0.f, acc3 = 0.f;
        for (int t = wid; t < L; t += 4) {
            const u16* src = (lane < 32) ? (hf + (size_t)t * HDIM + lane * 4)
                                         : (hb + (size_t)t * HDIM + (lane - 32) * 4);
            uint2 pv = *(const uint2*)src;
            const float w = sh_sc[t];
            acc0 += w * b2f((u16)(pv.x & 0xFFFF));
            acc1 += w * b2f((u16)(pv.x >> 16));
            acc2 += w * b2f((u16)(pv.y & 0xFFFF));
            acc3 += w * b2f((u16)(pv.y >> 16));
        }
        const int e0 = lane * 4;
        sh_part[wid * EDIM + e0]     = acc0;
        sh_part[wid * EDIM + e0 + 1] = acc1;
        sh_part[wid * EDIM + e0 + 2] = acc2;
        sh_part[wid * EDIM + e0 + 3] = acc3;
    }
    __syncthreads();

    {
        const float inv = 1.0f / sh_sum;
        sh_hl[tid] = (sh_part[tid] + sh_part[EDIM + tid] +
                      sh_part[2 * EDIM + tid] + sh_part[3 * EDIM + tid]) * inv;
    }
    __syncthreads();

    {   // Wv
        float s0 = b2f(bv[tid]), s1 = 0.0f;
        const u16* wr = wv + tid * EDIM;
#pragma unroll
        for (int ks = 0; ks < 32; ks += 2) {
            bf16x8 w8 = *(const bf16x8*)(wr + ks * 8);
            bf16x8 w9 = *(const bf16x8*)(wr + ks * 8 + 8);
#pragma unroll
            for (int d = 0; d < 8; ++d) {
                s0 += b2f((u16)w8[d]) * sh_hl[ks * 8 + d];
                s1 += b2f((u16)w9[d]) * sh_hl[ks * 8 + 8 + d];
            }
        }
        sh_uv[tid] = s0 + s1;
    }
    __syncthreads();

    {   // Wo
        float s0 = b2f(bo[tid]), s1 = 0.0f;
        const u16* wr = wo + tid * EDIM;
#pragma unroll
        for (int ks = 0; ks < 32; ks += 2) {
            bf16x8 w8 = *(const bf16x8*)(wr + ks * 8);
            bf16x8 w9 = *(const bf16x8*)(wr + ks * 8 + 8);
#pragma unroll
            for (int d = 0; d < 8; ++d) {
                s0 += b2f((u16)w8[d]) * sh_uv[ks * 8 + d];
                s1 += b2f((u16)w9[d]) * sh_uv[ks * 8 + 8 + d];
            }
        }
        sh_v1[tid] = s0 + s1;
    }
    __syncthreads();

    {   // Wl -> out
        float s0 = b2f(bl[tid]), s1 = 0.0f;
        const u16* wr = wl + tid * EDIM;
#pragma unroll
        for (int ks = 0; ks < 32; ks += 2) {
            bf16x8 w8 = *(const bf16x8*)(wr + ks * 8);
            bf16x8 w9 = *(const bf16x8*)(wr + ks * 8 + 8);
#pragma unroll
            for (int d = 0; d < 8; ++d) {
                s0 += b2f((u16)w8[d]) * sh_v1[ks * 8 + d];
                s1 += b2f((u16)w9[d]) * sh_v1[ks * 8 + 8 + d];
            }
        }
        const float s = s0 + s1;
        const size_t oidx = (size_t)n * EDIM + tid;
        if (flag) ((float*)outv)[oidx] = s;
        else      ((u16*)outv)[oidx]   = f2b(s);
    }
}

// -------------------------------------------------------------------------
extern "C" void kernel_launch(void* const* d_in, const int* in_sizes, int n_in,
                              void* d_out, int out_size, void* d_ws, size_t ws_size,
                              hipStream_t stream) {
    const int* x       = (const int*)d_in[0];
    const int* d_ids   = (const int*)d_in[1];
    const int* utt_len = (const int*)d_in[2];
    const void* f_arr[18] = {
        d_in[3],
        d_in[4], d_in[5], d_in[6], d_in[7],
        d_in[8], d_in[9], d_in[10], d_in[11],
        d_in[12], d_in[13],
        d_in[14],
        d_in[16], d_in[17],
        d_in[18], d_in[19],
        d_in[20], d_in[21]
    };

    k_detect<<<1, 64, 0, stream>>>(d_ws, d_ids, utt_len,
        f_arr[0], f_arr[1], f_arr[2], f_arr[3], f_arr[4], f_arr[5], f_arr[6], f_arr[7],
        f_arr[8], f_arr[9], f_arr[10], f_arr[11], f_arr[12], f_arr[13], f_arr[14],
        f_arr[15], f_arr[16], f_arr[17]);

    k_convert<<<1024, 256, 0, stream>>>(d_ws,
        f_arr[0], f_arr[1], f_arr[2], f_arr[3], f_arr[4], f_arr[5], f_arr[6], f_arr[7],
        f_arr[8], f_arr[9], f_arr[10], f_arr[11], f_arr[12], f_arr[13], f_arr[14],
        f_arr[15], f_arr[16], f_arr[17]);

    k_scan<<<dim3(NUTT / NBU, 2), 512, 0, stream>>>(x, d_ws);

    k_attn<<<NUTT, 256, 0, stream>>>(d_ws, d_out);
}

// Round 8
// 441.682 us; speedup vs baseline: 5.0012x; 1.0020x over previous
//
#include <hip/hip_runtime.h>
#include <hip/hip_bf16.h>
#include <math.h>
#include <stdint.h>

typedef unsigned short u16;
typedef unsigned int   u32;
typedef __attribute__((ext_vector_type(8))) short bf16x8;
typedef __attribute__((ext_vector_type(4))) float f32x4;

#define EDIM 256
#define HDIM 128
#define TLEN 128
#define NUTT 1024
#define UU   32
#define NBU  8

#define WS_FLAG 0
#define WS_LENS 64
#define WS_TAB  4608
#define WS_COPY 8192
#define WS_OF   18874368LL
#define WS_OB   52428800LL

#define MFMA16(a, b, c) __builtin_amdgcn_mfma_f32_16x16x32_bf16((a), (b), (c), 0, 0, 0)
#define SOUT(u, s, j) ((u) * 1096 + (s) * 136 + (j))

__constant__ int G_SZ[18] = {7680000, 98304, 49152, 384, 384, 98304, 49152, 384, 384,
                             65536, 256, 65536, 65536, 256, 65536, 256, 65536, 256};

__device__ __forceinline__ float b2f(u16 b) {
    u32 u = ((u32)b) << 16; float f; __builtin_memcpy(&f, &u, 4); return f;
}
__device__ __forceinline__ u16 f2b(float f) {   // RNE manual (cold paths)
    u32 u; __builtin_memcpy(&u, &f, 4);
    u32 r = u + 0x7FFFu + ((u >> 16) & 1u);
    return (u16)(r >> 16);
}
__device__ __forceinline__ u16 f2b_hw(float f) {  // hot path: HW cvt
    __hip_bfloat16 h = __float2bfloat16(f);
    u16 v; __builtin_memcpy(&v, &h, 2); return v;
}
__device__ __forceinline__ float fsigmoid(float x) { return 1.0f / (1.0f + __expf(-x)); }
__device__ __forceinline__ float ftanh(float x) { return 1.0f - 2.0f / (__expf(2.0f * x) + 1.0f); }

// -------------------------------------------------------------------------
__global__ void k_detect(void* ws,
                         const int* __restrict__ d_ids, const int* __restrict__ utt_len,
                         const void* a0, const void* a1, const void* a2, const void* a3,
                         const void* a4, const void* a5, const void* a6, const void* a7,
                         const void* a8, const void* a9, const void* a10, const void* a11,
                         const void* a12, const void* a13, const void* a14, const void* a15,
                         const void* a16, const void* a17) {
    const u16* p = (const u16*)a0;
    int cnt = 0;
    for (int i = threadIdx.x; i < 16384; i += 64)
        cnt += ((p[i] & 0x7F80) == 0x7F80) ? 1 : 0;
#pragma unroll
    for (int o = 32; o > 0; o >>= 1) cnt += __shfl_down(cnt, o);
    if (threadIdx.x == 0) {
        const void* orig[18] = {a0,a1,a2,a3,a4,a5,a6,a7,a8,a9,a10,a11,a12,a13,a14,a15,a16,a17};
        const int flag = (cnt > 0) ? 1 : 0;
        *(int*)((char*)ws + WS_FLAG) = flag;
        const u16** tab = (const u16**)((char*)ws + WS_TAB);
        char* base = (char*)ws + WS_COPY;
        long long cum = 0;
        for (int a = 0; a < 18; ++a) {
            tab[a] = flag ? (const u16*)(base + cum * 2) : (const u16*)orig[a];
            cum += G_SZ[a];
        }
    }
    int* lens = (int*)((char*)ws + WS_LENS);
    for (int n = threadIdx.x; n < NUTT; n += 64) {
        int b = n >> 5;
        int u = n & (UU - 1);
        int L = utt_len[d_ids[b] * UU + u];
        lens[n] = min(max(L, 1), TLEN);
    }
}

// -------------------------------------------------------------------------
__global__ void k_convert(void* ws,
                          const void* a0, const void* a1, const void* a2, const void* a3,
                          const void* a4, const void* a5, const void* a6, const void* a7,
                          const void* a8, const void* a9, const void* a10, const void* a11,
                          const void* a12, const void* a13, const void* a14, const void* a15,
                          const void* a16, const void* a17) {
    if (*(const int*)((const char*)ws + WS_FLAG) == 0) return;
    const void* orig[18] = {a0,a1,a2,a3,a4,a5,a6,a7,a8,a9,a10,a11,a12,a13,a14,a15,a16,a17};
    u16* base = (u16*)((char*)ws + WS_COPY);
    const int gtid = blockIdx.x * blockDim.x + threadIdx.x;
    const int gs   = gridDim.x * blockDim.x;
    long long cum = 0;
    for (int a = 0; a < 18; ++a) {
        const float4* src = (const float4*)orig[a];
        uint2* dst = (uint2*)(base + cum);
        const int n4 = G_SZ[a] >> 2;
        for (int i = gtid; i < n4; i += gs) {
            float4 v = src[i];
            uint2 pk;
            pk.x = (u32)f2b(v.x) | ((u32)f2b(v.y) << 16);
            pk.y = (u32)f2b(v.z) | ((u32)f2b(v.w) << 16);
            dst[i] = pk;
        }
        cum += G_SZ[a];
    }
}

// -------------------------------------------------------------------------
// k_scan: GRU scan, both directions. 8 utt/block, 512 thr, 256 blocks.
// Zero-vector MFMA chain start (no per-step acc-bias splat); r/z biases
// combined (exact: sig(xp+gh)), n-gate keeps separate b_ih/b_hh; HW bf16
// cvt in the gate phase. Emb prefetch via LDS; staged coalesced flush.
// -------------------------------------------------------------------------
__global__ __launch_bounds__(512)
void k_scan(const int* __restrict__ x, void* ws) {
    const u16* const* tab = (const u16* const*)((char*)ws + WS_TAB);
    const int dir = blockIdx.y;
    const u16* emb  = tab[0];
    const u16* w_ih = tab[1 + dir * 4];
    const u16* w_hh = tab[2 + dir * 4];
    const u16* b_ih = tab[3 + dir * 4];
    const u16* b_hh = tab[4 + dir * 4];
    u16* outp = (u16*)((char*)ws + (dir ? WS_OB : WS_OF));
    const int* lens = (const int*)((char*)ws + WS_LENS);

    const int n0 = blockIdx.x * NBU;
    __shared__ __align__(16) u16 sh_emb[2][NBU][264];
    __shared__ __align__(16) u16 sh_hi[2][NBU * 136];
    __shared__ __align__(16) u16 sh_lo[2][NBU * 136];
    __shared__ __align__(16) u16 sh_out[2][NBU * 1096];
    __shared__ int sh_tok[NBU * TLEN];
    __shared__ int sh_L[NBU];

    const int tid = threadIdx.x, lane = tid & 63, wvi = tid >> 6;
    const int q4 = lane >> 4, mm = lane & 15;
    const int j = wvi * 16 + mm;
    const int u8 = mm & 7;

    for (int i = tid; i < NBU * 136; i += 512) { sh_hi[0][i] = 0; sh_lo[0][i] = 0; }
    for (int i = tid; i < NBU * TLEN; i += 512) {
        const int u = i >> 7, tt = i & 127;
        sh_tok[i] = x[(n0 + u) * TLEN + tt];
    }
    if (tid < NBU) sh_L[tid] = lens[n0 + tid];

    bf16x8 wih[3][8]; bf16x8 whh[3][4];
    float bcr, bcz, bxn, bgn;
#pragma unroll
    for (int n3 = 0; n3 < 3; ++n3) {
        const int g = n3 * HDIM + j;
#pragma unroll
        for (int ks = 0; ks < 8; ++ks)
            wih[n3][ks] = *(const bf16x8*)(w_ih + g * EDIM + ks * 32 + q4 * 8);
#pragma unroll
        for (int ks = 0; ks < 4; ++ks)
            whh[n3][ks] = *(const bf16x8*)(w_hh + g * HDIM + ks * 32 + q4 * 8);
    }
    bcr = b2f(b_ih[j]) + b2f(b_hh[j]);
    bcz = b2f(b_ih[HDIM + j]) + b2f(b_hh[HDIM + j]);
    bxn = b2f(b_ih[2 * HDIM + j]);
    bgn = b2f(b_hh[2 * HDIM + j]);

    const int arr0 = (q4 & 2);
    float hprev[2] = {0.f, 0.f};
    const f32x4 zero4 = {0.f, 0.f, 0.f, 0.f};
    __syncthreads();

    const bool pwave = (wvi < 4);
    const int pf_u = lane & 7;
    const int pf_c = wvi * 8 + (lane >> 3);
    const int pf_L = sh_L[pf_u];

    uint4 pf;
    if (pwave) {
        const int te0 = dir ? (pf_L - 1) : 0;
        const int tok = sh_tok[pf_u * TLEN + te0];
        pf = *(const uint4*)(emb + (size_t)tok * EDIM + pf_c * 8);
        *(uint4*)&sh_emb[0][pf_u][pf_c * 8] = pf;
    }
    __syncthreads();

    for (int t = 0; t < TLEN; ++t) {
        const int cur = t & 1, nxt = cur ^ 1;
        const int obuf = (t >> 3) & 1, slot = t & 7;

        if (pwave && (t + 1 < TLEN)) {
            const int te = dir ? max(pf_L - 2 - t, 0) : (t + 1);
            const int tok = sh_tok[pf_u * TLEN + te];
            pf = *(const uint4*)(emb + (size_t)tok * EDIM + pf_c * 8);
        }

        f32x4 accx[3], accg[3];
        {
            bf16x8 a = *(const bf16x8*)&sh_emb[cur][u8][q4 * 8];
#pragma unroll
            for (int n3 = 0; n3 < 3; ++n3) accx[n3] = MFMA16(a, wih[n3][0], zero4);
        }
#pragma unroll
        for (int ks = 1; ks < 8; ++ks) {
            bf16x8 a = *(const bf16x8*)&sh_emb[cur][u8][ks * 32 + q4 * 8];
#pragma unroll
            for (int n3 = 0; n3 < 3; ++n3) accx[n3] = MFMA16(a, wih[n3][ks], accx[n3]);
        }
        {
            bf16x8 ahi = *(const bf16x8*)(sh_hi[cur] + u8 * 136 + q4 * 8);
            bf16x8 alo = *(const bf16x8*)(sh_lo[cur] + u8 * 136 + q4 * 8);
#pragma unroll
            for (int n3 = 0; n3 < 3; ++n3) {
                accg[n3] = MFMA16(ahi, whh[n3][0], zero4);
                accg[n3] = MFMA16(alo, whh[n3][0], accg[n3]);
            }
        }
#pragma unroll
        for (int ks = 1; ks < 4; ++ks) {
            bf16x8 ahi = *(const bf16x8*)(sh_hi[cur] + u8 * 136 + ks * 32 + q4 * 8);
            bf16x8 alo = *(const bf16x8*)(sh_lo[cur] + u8 * 136 + ks * 32 + q4 * 8);
#pragma unroll
            for (int n3 = 0; n3 < 3; ++n3) {
                accg[n3] = MFMA16(ahi, whh[n3][ks], accg[n3]);
                accg[n3] = MFMA16(alo, whh[n3][ks], accg[n3]);
            }
        }

#pragma unroll
        for (int rr2 = 0; rr2 < 2; ++rr2) {
            const int arr = rr2 + arr0;
            const int u   = (q4 * 4 + arr) & 7;
            const float r  = fsigmoid(accx[0][arr] + accg[0][arr] + bcr);
            const float z  = fsigmoid(accx[1][arr] + accg[1][arr] + bcz);
            const float nn = ftanh((accx[2][arr] + bxn) + r * (accg[2][arr] + bgn));
            const float hn = (1.0f - z) * nn + z * hprev[rr2];
            hprev[rr2] = hn;
            const u16 hb = f2b_hw(hn);
            sh_hi[nxt][u * 136 + j] = hb;
            sh_lo[nxt][u * 136 + j] = f2b_hw(hn - b2f(hb));
            sh_out[obuf][SOUT(u, slot, j)] = hb;
        }

        if (pwave && (t + 1 < TLEN))
            *(uint4*)&sh_emb[nxt][pf_u][pf_c * 8] = pf;

        __syncthreads();

        if (slot == 7) {
            const int rowIdx = tid >> 3;
            const int part   = tid & 7;
            const int fu = rowIdx >> 3, fs = rowIdx & 7;
            const int tt = (t & ~7) + fs;
            const int tout = dir ? (sh_L[fu] - 1 - tt) : tt;
            if (tout >= 0) {
                const u16* srcp = &sh_out[obuf][SOUT(fu, fs, part * 16)];
                uint4 v0 = *(const uint4*)(srcp);
                uint4 v1 = *(const uint4*)(srcp + 8);
                u16* dstp = outp + ((size_t)(n0 + fu) * TLEN + tout) * HDIM + part * 16;
                *(uint4*)(dstp)     = v0;
                *(uint4*)(dstp + 8) = v1;
            }
        }
    }
}

// -------------------------------------------------------------------------
// k_attn: single-pass per-wave online-softmax attention + epilogue.
// 1024 blocks x 256 threads. h rows read ONCE (67 MB total, was 134).
// -------------------------------------------------------------------------
__global__ __launch_bounds__(256)
void k_attn(void* ws, void* outv) {
    const u16* const* tab = (const u16* const*)((char*)ws + WS_TAB);
    const u16* wq = tab[9];  const u16* bq = tab[10];
    const u16* wk = tab[11];
    const u16* wv = tab[12]; const u16* bv = tab[13];
    const u16* wo = tab[14]; const u16* bo = tab[15];
    const u16* wl = tab[16]; const u16* bl = tab[17];
    const int* lens = (const int*)((char*)ws + WS_LENS);
    const int flag = *(const int*)((const char*)ws + WS_FLAG);

    const int n = blockIdx.x;
    const int L = lens[n];
    const u16* hf = (const u16*)((char*)ws + WS_OF) + (size_t)n * TLEN * HDIM;
    const u16* hb = (const u16*)((char*)ws + WS_OB) + (size_t)n * TLEN * HDIM;

    __shared__ float sh_hl[EDIM];      // h_last, then ctx
    __shared__ float sh_v1[EDIM];      // q, then Wo out
    __shared__ float sh_uv[EDIM];      // Wk^T q, then Wv out
    __shared__ float sh_a[4 * EDIM];   // per-wave online acc
    __shared__ float sh_m[4], sh_l[4];

    const int tid = threadIdx.x, lane = tid & 63, wid = tid >> 6;

    sh_hl[tid] = (tid < HDIM) ? b2f(hf[(size_t)(L - 1) * HDIM + tid])
                              : b2f(hb[(size_t)(L - 1) * HDIM + (tid - HDIM)]);
    __syncthreads();

    {   // q = Wq h_last + bq
        float s0 = b2f(bq[tid]), s1 = 0.0f;
        const u16* wr = wq + tid * EDIM;
#pragma unroll
        for (int ks = 0; ks < 32; ks += 2) {
            bf16x8 w8 = *(const bf16x8*)(wr + ks * 8);
            bf16x8 w9 = *(const bf16x8*)(wr + ks * 8 + 8);
#pragma unroll
            for (int d = 0; d < 8; ++d) {
                s0 += b2f((u16)w8[d]) * sh_hl[ks * 8 + d];
                s1 += b2f((u16)w9[d]) * sh_hl[ks * 8 + 8 + d];
            }
        }
        sh_v1[tid] = s0 + s1;
    }
    __syncthreads();

    {   // uv = Wk^T q
        float s0 = 0.0f, s1 = 0.0f;
        for (int i = 0; i < EDIM; i += 2) {
            s0 += b2f(wk[i * EDIM + tid]) * sh_v1[i];
            s1 += b2f(wk[(i + 1) * EDIM + tid]) * sh_v1[i + 1];
        }
        sh_uv[tid] = s0 + s1;
    }
    __syncthreads();

    // ---- single pass: score + online softmax + weighted accumulation
    {
        const int e0 = lane * 4;
        const float u0 = sh_uv[e0], u1 = sh_uv[e0 + 1];
        const float u2 = sh_uv[e0 + 2], u3 = sh_uv[e0 + 3];
        float m = -1e30f, l = 0.0f;
        float a0 = 0.f, a1 = 0.f, a2 = 0.f, a3 = 0.f;
        for (int t = wid; t < L; t += 4) {
            const u16* src = (lane < 32) ? (hf + (size_t)t * HDIM + lane * 4)
                                         : (hb + (size_t)t * HDIM + (lane - 32) * 4);
            uint2 pv = *(const uint2*)src;
            const float h0 = b2f((u16)(pv.x & 0xFFFF));
            const float h1 = b2f((u16)(pv.x >> 16));
            const float h2 = b2f((u16)(pv.y & 0xFFFF));
            const float h3 = b2f((u16)(pv.y >> 16));
            float p = h0 * u0 + h1 * u1 + h2 * u2 + h3 * u3;
#pragma unroll
            for (int o = 32; o > 0; o >>= 1) p += __shfl_xor(p, o);
            const float s = p * 0.0625f;       // / sqrt(256)
            const float mn = fmaxf(m, s);
            const float c = __expf(m - mn);
            const float w = __expf(s - mn);
            l = l * c + w;
            a0 = a0 * c + w * h0;
            a1 = a1 * c + w * h1;
            a2 = a2 * c + w * h2;
            a3 = a3 * c + w * h3;
            m = mn;
        }
        sh_a[wid * EDIM + e0]     = a0;
        sh_a[wid * EDIM + e0 + 1] = a1;
        sh_a[wid * EDIM + e0 + 2] = a2;
        sh_a[wid * EDIM + e0 + 3] = a3;
        if (lane == 0) { sh_m[wid] = m; sh_l[wid] = l; }
    }
    __syncthreads();

    {   // merge 4 waves: ctx[e] = sum_w c_w a_w[e] / sum_w c_w l_w
        const float m0 = sh_m[0], m1 = sh_m[1], m2 = sh_m[2], m3 = sh_m[3];
        const float M = fmaxf(fmaxf(m0, m1), fmaxf(m2, m3));
        const float c0 = __expf(m0 - M), c1 = __expf(m1 - M);
        const float c2 = __expf(m2 - M), c3 = __expf(m3 - M);
        const float den = c0 * sh_l[0] + c1 * sh_l[1] + c2 * sh_l[2] + c3 * sh_l[3];
        const float num = c0 * sh_a[tid] + c1 * sh_a[EDIM + tid] +
                          c2 * sh_a[2 * EDIM + tid] + c3 * sh_a[3 * EDIM + tid];
        sh_hl[tid] = num / den;
    }
    __syncthreads();

    {   // Wv
        float s0 = b2f(bv[tid]), s1 = 0.0f;
        const u16* wr = wv + tid * EDIM;
#pragma unroll
        for (int ks = 0; ks < 32; ks += 2) {
            bf16x8 w8 = *(const bf16x8*)(wr + ks * 8);
            bf16x8 w9 = *(const bf16x8*)(wr + ks * 8 + 8);
#pragma unroll
            for (int d = 0; d < 8; ++d) {
                s0 += b2f((u16)w8[d]) * sh_hl[ks * 8 + d];
                s1 += b2f((u16)w9[d]) * sh_hl[ks * 8 + 8 + d];
            }
        }
        sh_uv[tid] = s0 + s1;
    }
    __syncthreads();

    {   // Wo
        float s0 = b2f(bo[tid]), s1 = 0.0f;
        const u16* wr = wo + tid * EDIM;
#pragma unroll
        for (int ks = 0; ks < 32; ks += 2) {
            bf16x8 w8 = *(const bf16x8*)(wr + ks * 8);
            bf16x8 w9 = *(const bf16x8*)(wr + ks * 8 + 8);
#pragma unroll
            for (int d = 0; d < 8; ++d) {
                s0 += b2f((u16)w8[d]) * sh_uv[ks * 8 + d];
                s1 += b2f((u16)w9[d]) * sh_uv[ks * 8 + 8 + d];
            }
        }
        sh_v1[tid] = s0 + s1;
    }
    __syncthreads();

    {   // Wl -> out
        float s0 = b2f(bl[tid]), s1 = 0.0f;
        const u16* wr = wl + tid * EDIM;
#pragma unroll
        for (int ks = 0; ks < 32; ks += 2) {
            bf16x8 w8 = *(const bf16x8*)(wr + ks * 8);
            bf16x8 w9 = *(const bf16x8*)(wr + ks * 8 + 8);
#pragma unroll
            for (int d = 0; d < 8; ++d) {
                s0 += b2f((u16)w8[d]) * sh_v1[ks * 8 + d];
                s1 += b2f((u16)w9[d]) * sh_v1[ks * 8 + 8 + d];
            }
        }
        const float s = s0 + s1;
        const size_t oidx = (size_t)n * EDIM + tid;
        if (flag) ((float*)outv)[oidx] = s;
        else      ((u16*)outv)[oidx]   = f2b(s);
    }
}

// -------------------------------------------------------------------------
extern "C" void kernel_launch(void* const* d_in, const int* in_sizes, int n_in,
                              void* d_out, int out_size, void* d_ws, size_t ws_size,
                              hipStream_t stream) {
    const int* x       = (const int*)d_in[0];
    const int* d_ids   = (const int*)d_in[1];
    const int* utt_len = (const int*)d_in[2];
    const void* f_arr[18] = {
        d_in[3],
        d_in[4], d_in[5], d_in[6], d_in[7],
        d_in[8], d_in[9], d_in[10], d_in[11],
        d_in[12], d_in[13],
        d_in[14],
        d_in[16], d_in[17],
        d_in[18], d_in[19],
        d_in[20], d_in[21]
    };

    k_detect<<<1, 64, 0, stream>>>(d_ws, d_ids, utt_len,
        f_arr[0], f_arr[1], f_arr[2], f_arr[3], f_arr[4], f_arr[5], f_arr[6], f_arr[7],
        f_arr[8], f_arr[9], f_arr[10], f_arr[11], f_arr[12], f_arr[13], f_arr[14],
        f_arr[15], f_arr[16], f_arr[17]);

    k_convert<<<1024, 256, 0, stream>>>(d_ws,
        f_arr[0], f_arr[1], f_arr[2], f_arr[3], f_arr[4], f_arr[5], f_arr[6], f_arr[7],
        f_arr[8], f_arr[9], f_arr[10], f_arr[11], f_arr[12], f_arr[13], f_arr[14],
        f_arr[15], f_arr[16], f_arr[17]);

    k_scan<<<dim3(NUTT / NBU, 2), 512, 0, stream>>>(x, d_ws);

    k_attn<<<NUTT, 256, 0, stream>>>(d_ws, d_out);
}